// Round 11
// baseline (364.597 us; speedup 1.0000x reference)
//
#include <hip/hip_runtime.h>
#include <hip/hip_bf16.h>
#include <cstdint>
#include <cstddef>
#include <cmath>

typedef unsigned short bf16u;
typedef float f32x4 __attribute__((ext_vector_type(4)));
typedef short frag8 __attribute__((ext_vector_type(8)));

typedef __attribute__((address_space(1))) uint32_t u32g;
typedef __attribute__((address_space(3))) uint32_t u32l;

__device__ __forceinline__ void async_cp16(const bf16u* g, bf16u* l) {
    __builtin_amdgcn_global_load_lds((u32g*)g, (u32l*)l, 16, 0, 0);
}

__device__ __forceinline__ bf16u f2bf(float f) {
    union { float f; uint32_t u; } v; v.f = f;
    uint32_t u = v.u;
    return (bf16u)((u + 0x7fffu + ((u >> 16) & 1u)) >> 16);   // RNE
}

__device__ __forceinline__ uint32_t pk2bf(float a, float b) {
    __hip_bfloat162 h = __float22bfloat162_rn(make_float2(a, b));  // v_cvt_pk_bf16_f32
    union { __hip_bfloat162 h; uint32_t u; } c; c.h = h; return c.u;
}

// key permutation within each 64-block of the key axis: slot = (k&15)*4 + (k>>4)&3
__device__ __forceinline__ int vperm(int n) {
    return (n & ~63) | ((n & 15) << 2) | ((n >> 4) & 3);
}

// ---------------------------------------------------------------------------
// Compile-time tables (4 scales)
// ---------------------------------------------------------------------------
static constexpr int cN[4]   = {784, 784, 196, 49};
static constexpr int cE[4]   = {384, 192, 384, 768};
static constexpr int cM[4]   = {12544, 12544, 3136, 784};
static constexpr int cC[4]   = {96, 192, 384, 768};
static constexpr int cH[4]   = {56, 28, 14, 7};
static constexpr int cS[4]   = {2, 1, 1, 1};
static constexpr int cWt[4]  = {28, 28, 14, 7};

static constexpr size_t xoff[4] = {0, 4816896, 7225344, 8429568};   // M*E cumsum (also out offs)
static constexpr size_t voff[4] = {0, 6815744, 10223616, 12320768}; // 128*DHP*NJ cumsum
static constexpr size_t woff[4] = {0, 589824, 737280, 1327104};     // 4*E^2 cumsum

// scale * log2(e)  (exp2-domain softmax)
__device__ __constant__ float qsc[4] = {0.20823509f, 0.29448888f, 0.20823509f, 0.14724444f};

// HALF-M tile counts (64-row tiles, 128-col panels):
// s0: 196x3=588, s2: 49x3=147, s3: 13x6=78, s1(kv64/tile64 64x64): 196x3=588
static constexpr int hStart[5] = {0, 588, 735, 813, 1401};
// ounf union: s0(128,294), s2(128,75), s3(128,42), s1(64,588)
static constexpr int oStart[5]  = {0,294,369,411,999};

static constexpr int fStart[9] = {0,4800,9600,12000,14400,15744,17088,17856,18624};
static constexpr int wCum[17]  = {0,72,144,216,288,306,324,342,360,432,504,576,648,936,1224,1512,1800};
static constexpr int fNtn[4] = {25, 25, 7, 2};
static constexpr int fNtc[4] = {3, 6, 12, 24};
static constexpr int fSp[4]  = {4, 1, 1, 1};

struct BiasP { const float* p[16]; };
struct PrepP { const float* x[8]; const float* w[16]; };
struct OunfP { const float* xd[4]; };

// ---------------------------------------------------------------------------
// prep: 8 flatten-transposes (fp32 -> bf16) + 16 weight converts (unchanged)
// ---------------------------------------------------------------------------
__global__ __launch_bounds__(256) void prep(PrepP pp, bf16u* __restrict__ Xd,
                                            bf16u* __restrict__ Xc, bf16u* __restrict__ Wb) {
    int blk = blockIdx.x, tid = threadIdx.x;
    if (blk < 18624) {
        __shared__ float tile[32][33];
        int seg = 0;
        while (seg < 7 && blk >= fStart[seg + 1]) seg++;
        int s = seg >> 1, which = seg & 1;
        int l = blk - fStart[seg];
        int ntn = fNtn[s], ntc = fNtc[s], sp = fSp[s];
        int nt = l % ntn; l /= ntn;
        int ctl = l % ntc; l /= ntc;
        int spi = l % sp; int b = l / sp;
        int sv = cS[s];
        int s1i = spi / sv, s2i = spi % sv;
        int C = cC[s], H = cH[s], Wd = cH[s], N = cN[s], E2 = cE[s], Wt = cWt[s];
        const float* x = pp.x[s * 2 + which];
        bf16u* dst = (which ? Xc : Xd) + xoff[s];
        int tx = tid & 31, ty = tid >> 5;
        int n0 = nt * 32, c0 = ctl * 32;
#pragma unroll
        for (int rr = 0; rr < 4; ++rr) {
            int c = c0 + rr * 8 + ty;
            int n = n0 + tx;
            if (n < N) {
                int hh = (n / Wt) * sv + s1i;
                int ww = (n % Wt) * sv + s2i;
                tile[rr * 8 + ty][tx] = x[((size_t)(b * C + c) * H + hh) * Wd + ww];
            }
        }
        __syncthreads();
        int ebase = (s1i * sv + s2i) * C + c0;
#pragma unroll
        for (int rr = 0; rr < 4; ++rr) {
            int n = n0 + rr * 8 + ty;
            if (n < N)
                dst[((size_t)b * N + n) * E2 + ebase + tx] = f2bf(tile[tx][rr * 8 + ty]);
        }
    } else {
        int wb = blk - 18624;
        int m2 = 0;
        while (m2 < 15 && wb >= wCum[m2 + 1]) m2++;
        int s = m2 >> 2, mi = m2 & 3;
        size_t e2 = (size_t)cE[s] * cE[s];
        size_t base = (size_t)(wb - wCum[m2]) * 2048 + tid * 8;
        const float* src = pp.w[m2];
        bf16u* dst = Wb + woff[s] + mi * e2 + base;
        float4 a = *(const float4*)(src + base);
        float4 c = *(const float4*)(src + base + 4);
        bf16u o[8] = {f2bf(a.x), f2bf(a.y), f2bf(a.z), f2bf(a.w),
                      f2bf(c.x), f2bf(c.y), f2bf(c.z), f2bf(c.w)};
        *(frag8*)dst = *(frag8*)o;
    }
}

// ---------------------------------------------------------------------------
// HALF-M Q tile: 64 rows x 128 cols, single-buffered (schedule proven
// neutral). 4 waves: wm in {0,32}, wn in {0,64}. acc 2x4 -> half the VGPRs
// of the old 128-row tile -> more waves/CU (round-10 diagnosis: qkv is
// concurrency-limited memory throughput, ~1.5 waves/SIMD resident).
// LDS: A 2048 + W 4096 = 6144 elems (12KB).
// ---------------------------------------------------------------------------
__device__ __forceinline__ void gemm_q_h(const bf16u* __restrict__ A, const bf16u* __restrict__ W,
                                         const float* __restrict__ bias,
                                         int M, int E, int mTile, int eTile, float oscale,
                                         bf16u* __restrict__ outB, bf16u* sm) {
    bf16u* As = sm;          // 64 x 32
    bf16u* Bs = sm + 2048;   // 128 x 32
    int tid = threadIdx.x, wave = tid >> 6, lane = tid & 63;
    int mbase = mTile * 64, ebase = eTile * 128;
    int wm = (wave & 1) * 32, wn = (wave >> 1) * 64;
    f32x4 acc[2][4] = {};
    int srow = tid >> 2, sch = (tid & 3) * 8;
    int K = E;
    int m = mbase + srow; if (m >= M) m = M - 1;
    const bf16u* Ag  = A + (size_t)m * K + sch;
    const bf16u* Wg0 = W + (size_t)(ebase + srow) * K + sch;
    const bf16u* Wg1 = W + (size_t)(ebase + srow + 64) * K + sch;
    int la = (lane & 15) * 32 + (lane >> 4) * 8;

    for (int k0 = 0; k0 < K; k0 += 32) {
        async_cp16(Ag + k0, As + tid * 8);
        async_cp16(Wg0 + k0, Bs + tid * 8);
        async_cp16(Wg1 + k0, Bs + 2048 + tid * 8);
        __syncthreads();
        frag8 af[2], bfr[4];
#pragma unroll
        for (int i = 0; i < 2; ++i)
            af[i] = *(const frag8*)(As + (wm + i * 16) * 32 + la);
#pragma unroll
        for (int j = 0; j < 4; ++j)
            bfr[j] = *(const frag8*)(Bs + (wn + j * 16) * 32 + la);
#pragma unroll
        for (int i = 0; i < 2; ++i)
#pragma unroll
            for (int j = 0; j < 4; ++j)
                acc[i][j] = __builtin_amdgcn_mfma_f32_16x16x32_bf16(af[i], bfr[j], acc[i][j], 0, 0, 0);
        __syncthreads();
    }

    int mrow = lane & 15, quad = lane >> 4;
#pragma unroll
    for (int mt = 0; mt < 2; ++mt) {
#pragma unroll
        for (int nt = 0; nt < 4; ++nt) {
            int col = ebase + wn + nt * 16 + mrow;
            float bv = bias[col];
            int rbase = mbase + wm + mt * 16 + quad * 4;
#pragma unroll
            for (int r = 0; r < 4; ++r) {
                int rowg = rbase + r;
                if (rowg >= M) continue;
                outB[(size_t)rowg * E + col] = f2bf((acc[mt][nt][r] + bv) * oscale);
            }
        }
    }
}

// ---------------------------------------------------------------------------
// HALF-M fused K+V tile: 64 rows x 128 cols, single-buffered.
// acc 2x(2x4) = 16 f32x4. LDS: A 2048 + K 4096 + V 4096 = 10240 elems (20KB).
// ---------------------------------------------------------------------------
template<int NN, int DHt, int DHPt, int NJt>
__device__ __forceinline__ void gemm_kv_h(const bf16u* __restrict__ A, const bf16u* __restrict__ Wk,
                                          const bf16u* __restrict__ Wv,
                                          const float* __restrict__ bk, const float* __restrict__ bv,
                                          int M, int E, int mTile, int eTile,
                                          bf16u* __restrict__ Ko, bf16u* __restrict__ Vo, bf16u* sm) {
    bf16u* As = sm;          // 64 x 32
    bf16u* Ks = sm + 2048;   // 128 x 32
    bf16u* Vs = sm + 6144;   // 128 x 32
    int tid = threadIdx.x, wave = tid >> 6, lane = tid & 63;
    int mbase = mTile * 64, ebase = eTile * 128;
    int wm = (wave & 1) * 32, wn = (wave >> 1) * 64;
    f32x4 acck[2][4] = {};
    f32x4 accv[2][4] = {};
    int srow = tid >> 2, sch = (tid & 3) * 8;
    int Kd = E;
    int m = mbase + srow; if (m >= M) m = M - 1;
    const bf16u* Ag  = A + (size_t)m * Kd + sch;
    const bf16u* Kg0 = Wk + (size_t)(ebase + srow) * Kd + sch;
    const bf16u* Kg1 = Wk + (size_t)(ebase + srow + 64) * Kd + sch;
    const bf16u* Vg0 = Wv + (size_t)(ebase + srow) * Kd + sch;
    const bf16u* Vg1 = Wv + (size_t)(ebase + srow + 64) * Kd + sch;
    int la = (lane & 15) * 32 + (lane >> 4) * 8;

    for (int k0 = 0; k0 < Kd; k0 += 32) {
        async_cp16(Ag + k0, As + tid * 8);
        async_cp16(Kg0 + k0, Ks + tid * 8);
        async_cp16(Kg1 + k0, Ks + 2048 + tid * 8);
        async_cp16(Vg0 + k0, Vs + tid * 8);
        async_cp16(Vg1 + k0, Vs + 2048 + tid * 8);
        __syncthreads();
        frag8 af[2], bfr[4];
#pragma unroll
        for (int i = 0; i < 2; ++i)
            af[i] = *(const frag8*)(As + (wm + i * 16) * 32 + la);
#pragma unroll
        for (int j = 0; j < 4; ++j)
            bfr[j] = *(const frag8*)(Ks + (wn + j * 16) * 32 + la);
#pragma unroll
        for (int i = 0; i < 2; ++i)
#pragma unroll
            for (int j = 0; j < 4; ++j)
                acck[i][j] = __builtin_amdgcn_mfma_f32_16x16x32_bf16(af[i], bfr[j], acck[i][j], 0, 0, 0);
#pragma unroll
        for (int j = 0; j < 4; ++j)
            bfr[j] = *(const frag8*)(Vs + (wn + j * 16) * 32 + la);
#pragma unroll
        for (int i = 0; i < 2; ++i)
#pragma unroll
            for (int j = 0; j < 4; ++j)
                accv[i][j] = __builtin_amdgcn_mfma_f32_16x16x32_bf16(af[i], bfr[j], accv[i][j], 0, 0, 0);
        __syncthreads();
    }

    int mrow = lane & 15, quad = lane >> 4;
#pragma unroll
    for (int mt = 0; mt < 2; ++mt) {
#pragma unroll
        for (int nt = 0; nt < 4; ++nt) {
            int col = ebase + wn + nt * 16 + mrow;
            float bkc = bk[col];
            float bvc = bv[col];
            int hh = col / DHt, d = col - hh * DHt;
            int rbase = mbase + wm + mt * 16 + quad * 4;
#pragma unroll
            for (int r = 0; r < 4; ++r) {
                int rowg = rbase + r;
                if (rowg >= M) continue;
                Ko[(size_t)rowg * E + col] = f2bf(acck[mt][nt][r] + bkc);
                int bb2 = rowg / NN, n = rowg % NN;
                Vo[((size_t)(bb2 * 8 + hh) * DHPt + d) * NJt + vperm(n)] = f2bf(accv[mt][nt][r] + bvc);
            }
        }
    }
}

// ---------------------------------------------------------------------------
// s1 (E=192) 64x64 tiles, single-buffered (from round-9)
// ---------------------------------------------------------------------------
__device__ __forceinline__ void gemm_q64_s1(const bf16u* __restrict__ A, const bf16u* __restrict__ W,
                                            const float* __restrict__ bias,
                                            int M, int E, int mTile, int eTile, float oscale,
                                            bf16u* __restrict__ outB, bf16u* sm) {
    bf16u* As = sm;
    bf16u* Bs = sm + 2048;
    int tid = threadIdx.x, wave = tid >> 6, lane = tid & 63;
    int mbase = mTile * 64, ebase = eTile * 64;
    int wm = (wave & 1) * 32, wn = (wave >> 1) * 32;
    f32x4 acc[2][2] = {};
    int srow = tid >> 2, sch = (tid & 3) * 8;
    int K = E;
    int m = mbase + srow; if (m >= M) m = M - 1;
    const bf16u* Ag = A + (size_t)m * K + sch;
    const bf16u* Wg = W + (size_t)(ebase + srow) * K + sch;
    int la = (lane & 15) * 32 + (lane >> 4) * 8;

    for (int k0 = 0; k0 < K; k0 += 32) {
        async_cp16(Ag + k0, As + tid * 8);
        async_cp16(Wg + k0, Bs + tid * 8);
        __syncthreads();
        frag8 af0 = *(const frag8*)(As + wm * 32 + la);
        frag8 af1 = *(const frag8*)(As + (wm + 16) * 32 + la);
        frag8 bf0 = *(const frag8*)(Bs + wn * 32 + la);
        frag8 bf1 = *(const frag8*)(Bs + (wn + 16) * 32 + la);
        acc[0][0] = __builtin_amdgcn_mfma_f32_16x16x32_bf16(af0, bf0, acc[0][0], 0, 0, 0);
        acc[0][1] = __builtin_amdgcn_mfma_f32_16x16x32_bf16(af0, bf1, acc[0][1], 0, 0, 0);
        acc[1][0] = __builtin_amdgcn_mfma_f32_16x16x32_bf16(af1, bf0, acc[1][0], 0, 0, 0);
        acc[1][1] = __builtin_amdgcn_mfma_f32_16x16x32_bf16(af1, bf1, acc[1][1], 0, 0, 0);
        __syncthreads();
    }

    int mrow = lane & 15, quad = lane >> 4;
#pragma unroll
    for (int mt = 0; mt < 2; ++mt) {
#pragma unroll
        for (int nt = 0; nt < 2; ++nt) {
            int col = ebase + wn + nt * 16 + mrow;
            float bv = bias[col];
            int rbase = mbase + wm + mt * 16 + quad * 4;
#pragma unroll
            for (int r = 0; r < 4; ++r) {
                int rowg = rbase + r;
                if (rowg >= M) continue;
                outB[(size_t)rowg * E + col] = f2bf((acc[mt][nt][r] + bv) * oscale);
            }
        }
    }
}

template<int NN, int DHt, int DHPt, int NJt>
__device__ __forceinline__ void gemm_kv64(const bf16u* __restrict__ A, const bf16u* __restrict__ Wk,
                                          const bf16u* __restrict__ Wv,
                                          const float* __restrict__ bk, const float* __restrict__ bv,
                                          int M, int E, int mTile, int eTile,
                                          bf16u* __restrict__ Ko, bf16u* __restrict__ Vo, bf16u* sm) {
    bf16u* As = sm;
    bf16u* Ks = sm + 2048;
    bf16u* Vs = sm + 4096;
    int tid = threadIdx.x, wave = tid >> 6, lane = tid & 63;
    int mbase = mTile * 64, ebase = eTile * 64;
    int wm = (wave & 1) * 32, wn = (wave >> 1) * 32;
    f32x4 acck[2][2] = {};
    f32x4 accv[2][2] = {};
    int srow = tid >> 2, sch = (tid & 3) * 8;
    int Kd = E;
    int m = mbase + srow; if (m >= M) m = M - 1;
    const bf16u* Ag = A + (size_t)m * Kd + sch;
    const bf16u* Kg = Wk + (size_t)(ebase + srow) * Kd + sch;
    const bf16u* Vg = Wv + (size_t)(ebase + srow) * Kd + sch;
    int la = (lane & 15) * 32 + (lane >> 4) * 8;

    for (int k0 = 0; k0 < Kd; k0 += 32) {
        async_cp16(Ag + k0, As + tid * 8);
        async_cp16(Kg + k0, Ks + tid * 8);
        async_cp16(Vg + k0, Vs + tid * 8);
        __syncthreads();
        frag8 af0 = *(const frag8*)(As + wm * 32 + la);
        frag8 af1 = *(const frag8*)(As + (wm + 16) * 32 + la);
        frag8 k0f = *(const frag8*)(Ks + wn * 32 + la);
        frag8 k1f = *(const frag8*)(Ks + (wn + 16) * 32 + la);
        acck[0][0] = __builtin_amdgcn_mfma_f32_16x16x32_bf16(af0, k0f, acck[0][0], 0, 0, 0);
        acck[0][1] = __builtin_amdgcn_mfma_f32_16x16x32_bf16(af0, k1f, acck[0][1], 0, 0, 0);
        acck[1][0] = __builtin_amdgcn_mfma_f32_16x16x32_bf16(af1, k0f, acck[1][0], 0, 0, 0);
        acck[1][1] = __builtin_amdgcn_mfma_f32_16x16x32_bf16(af1, k1f, acck[1][1], 0, 0, 0);
        frag8 v0f = *(const frag8*)(Vs + wn * 32 + la);
        frag8 v1f = *(const frag8*)(Vs + (wn + 16) * 32 + la);
        accv[0][0] = __builtin_amdgcn_mfma_f32_16x16x32_bf16(af0, v0f, accv[0][0], 0, 0, 0);
        accv[0][1] = __builtin_amdgcn_mfma_f32_16x16x32_bf16(af0, v1f, accv[0][1], 0, 0, 0);
        accv[1][0] = __builtin_amdgcn_mfma_f32_16x16x32_bf16(af1, v0f, accv[1][0], 0, 0, 0);
        accv[1][1] = __builtin_amdgcn_mfma_f32_16x16x32_bf16(af1, v1f, accv[1][1], 0, 0, 0);
        __syncthreads();
    }

    int mrow = lane & 15, quad = lane >> 4;
#pragma unroll
    for (int mt = 0; mt < 2; ++mt) {
#pragma unroll
        for (int nt = 0; nt < 2; ++nt) {
            int col = ebase + wn + nt * 16 + mrow;
            float bkc = bk[col];
            float bvc = bv[col];
            int hh = col / DHt, d = col - hh * DHt;
            int rbase = mbase + wm + mt * 16 + quad * 4;
#pragma unroll
            for (int r = 0; r < 4; ++r) {
                int rowg = rbase + r;
                if (rowg >= M) continue;
                Ko[(size_t)rowg * E + col] = f2bf(acck[mt][nt][r] + bkc);
                int bb2 = rowg / NN, n = rowg % NN;
                Vo[((size_t)(bb2 * 8 + hh) * DHPt + d) * NJt + vperm(n)] = f2bf(accv[mt][nt][r] + bvc);
            }
        }
    }
}

// ---------------------------------------------------------------------------
// MERGED QKV, half-M tiles: blocks 0..1400 = K+V, 1401..2801 = Q.
// Grid 2802 (was 1998), LDS 20KB (was 32-72), acc VGPRs halved,
// launch_bounds(256,4) caps regalloc at 128 VGPR -> target 4+ blocks/CU.
// ---------------------------------------------------------------------------
__global__ __launch_bounds__(256, 4) void qkv_all(const bf16u* __restrict__ Xd, const bf16u* __restrict__ Xc,
                                                  const bf16u* __restrict__ Wb,
                                                  bf16u* __restrict__ Qb, bf16u* __restrict__ Kb,
                                                  bf16u* __restrict__ Vt, BiasP bp) {
    __shared__ __align__(16) bf16u sm[10240];   // 20KB union (kv_h)
    int blk0 = blockIdx.x;
    if (blk0 < 1401) {
        // ---- K+V path ----
        int blk = blk0;
        int seg = 0;
        while (seg < 3 && blk >= hStart[seg + 1]) seg++;
        int t = blk - hStart[seg];
        if (seg < 3) {
            int s = (seg == 0) ? 0 : (seg == 1 ? 2 : 3);
            int E = cE[s], M = cM[s];
            int ct = E >> 7;
            int mTile = t / ct, eTile = t - mTile * ct;
            const bf16u* A  = Xd + xoff[s];
            const bf16u* Wk = Wb + woff[s] + (size_t)1 * E * E;
            const bf16u* Wv = Wb + woff[s] + (size_t)2 * E * E;
            if (s == 0)
                gemm_kv_h<784, 48, 64, 832>(A, Wk, Wv, bp.p[1], bp.p[2], M, E, mTile, eTile,
                                            Kb + xoff[0], Vt + voff[0], sm);
            else if (s == 2)
                gemm_kv_h<196, 48, 64, 256>(A, Wk, Wv, bp.p[9], bp.p[10], M, E, mTile, eTile,
                                            Kb + xoff[2], Vt + voff[2], sm);
            else
                gemm_kv_h<49, 96, 96, 64>(A, Wk, Wv, bp.p[13], bp.p[14], M, E, mTile, eTile,
                                          Kb + xoff[3], Vt + voff[3], sm);
        } else {
            int E = 192, M = 12544;
            int mTile = t / 3, eTile = t - mTile * 3;
            gemm_kv64<784, 24, 32, 832>(Xd + xoff[1], Wb + woff[1] + (size_t)1 * E * E,
                                        Wb + woff[1] + (size_t)2 * E * E, bp.p[5], bp.p[6],
                                        M, E, mTile, eTile, Kb + xoff[1], Vt + voff[1], sm);
        }
    } else {
        // ---- Q path ----
        int blk = blk0 - 1401;
        int seg = 0;
        while (seg < 3 && blk >= hStart[seg + 1]) seg++;
        int t = blk - hStart[seg];
        if (seg < 3) {
            int s = (seg == 0) ? 0 : (seg == 1 ? 2 : 3);
            int E = cE[s], M = cM[s];
            int ct = E >> 7;
            int mTile = t / ct, eTile = t - mTile * ct;
            gemm_q_h(Xc + xoff[s], Wb + woff[s], bp.p[s * 4], M, E, mTile, eTile,
                     qsc[s], Qb + xoff[s], sm);
        } else {
            int E = 192, M = 12544;
            int mTile = t / 3, eTile = t - mTile * 3;
            gemm_q64_s1(Xc + xoff[1], Wb + woff[1], bp.p[4], M, E, mTile, eTile,
                        qsc[1], Qb + xoff[1], sm);
        }
    }
}

// ---------------------------------------------------------------------------
// Flash attention v3 (Q-tile 128, two 16-row frags/wave) + merged s3 path.
// (Unchanged)
// ---------------------------------------------------------------------------
__device__ __forceinline__ f32x4 bfly_add16(f32x4 v) {
#pragma unroll
    for (int m = 1; m <= 8; m <<= 1) {
        f32x4 o;
#pragma unroll
        for (int e = 0; e < 4; ++e) o[e] = __shfl_xor(v[e], m);
#pragma unroll
        for (int e = 0; e < 4; ++e) v[e] += o[e];
    }
    return v;
}

template<int DH, int N>
__device__ __forceinline__ void attn_body3(bf16u* __restrict__ smem,
                                           const bf16u* __restrict__ Q, const bf16u* __restrict__ K,
                                           const bf16u* __restrict__ Vt, bf16u* __restrict__ O,
                                           int lin) {
    constexpr int DHP = (DH == 24) ? 32 : 64;
    constexpr int C8  = DHP / 8;            // 4 or 8
    constexpr int CM  = C8 - 1;
    constexpr int KC  = DHP / 32;           // 1 or 2
    constexpr int DHT = (DH + 15) / 16;     // 2 or 3
    constexpr int VR  = DHT * 16;           // 32 or 48
    constexpr int NT  = (N + 63) / 64;      // KV tiles
    constexpr int QT  = (N + 127) / 128;    // Q tiles (128 rows/block)
    constexpr int NJc = NT * 64;
    constexpr int E   = DH * 8;
    constexpr int KS  = 64 * C8;            // 16B slots for K tile
    constexpr int TS  = KS + VR * 8;        // + V slots
    constexpr int RND = (TS + 255) / 256;
    constexpr int PP  = 72;

    bf16u* buf0 = smem;
    bf16u* buf1 = smem + (size_t)TS * 8;
    bf16u* Ps   = smem + (size_t)2 * TS * 8;

    const int qt = lin % QT;
    const int r2 = lin / QT;
    const int h = r2 & 7, b = r2 >> 3;
    const int qb = qt * 128;
    const int tid = threadIdx.x, wave = tid >> 6, lane = tid & 63;
    const int mrow = lane & 15, quad = lane >> 4;

    const bf16u* Kb2 = K + (size_t)b * N * E + h * DH;
    const bf16u* Vb2 = Vt + (size_t)(b * 8 + h) * DHP * NJc;

    auto stage = [&](int jt, bf16u* buf) {
#pragma unroll
        for (int r = 0; r < RND; ++r) {
            int s = tid + r * 256;
            bf16u* dst = buf + (size_t)s * 8;
            if (s < KS) {
                int row = s / C8;
                int cl = (s & CM) ^ (row & CM);
                int n = jt * 64 + row; if (n >= N) n = N - 1;
                async_cp16(Kb2 + (size_t)n * E + cl * 8, dst);
            } else if (s < TS) {
                int v = s - KS;
                int d = v >> 3;
                int cl = (v & 7) ^ (d & 7);
                async_cp16(Vb2 + (size_t)d * NJc + jt * 64 + cl * 8, dst);
            }
        }
    };

    stage(0, buf0);

    // Q fragments (two 16-row halves per wave), pre-scaled by scale*log2e
    frag8 qf0[KC], qf1[KC];
    {
        int qn0 = qb + wave * 32 + mrow;      if (qn0 >= N) qn0 = N - 1;
        int qn1 = qb + wave * 32 + 16 + mrow; if (qn1 >= N) qn1 = N - 1;
        const bf16u* qp0 = Q + (size_t)(b * N + qn0) * E + h * DH;
        const bf16u* qp1 = Q + (size_t)(b * N + qn1) * E + h * DH;
#pragma unroll
        for (int kc = 0; kc < KC; ++kc) {
            int col = kc * 32 + quad * 8;
            frag8 v0 = {}, v1 = {};
            if (col < DH) { v0 = *(const frag8*)(qp0 + col); v1 = *(const frag8*)(qp1 + col); }
            qf0[kc] = v0; qf1[kc] = v1;
        }
    }

    f32x4 lrun0 = {0.f, 0.f, 0.f, 0.f};
    f32x4 lrun1 = {0.f, 0.f, 0.f, 0.f};
    f32x4 oacc0[DHT], oacc1[DHT];
#pragma unroll
    for (int t = 0; t < DHT; ++t) { oacc0[t] = f32x4{0.f,0.f,0.f,0.f}; oacc1[t] = f32x4{0.f,0.f,0.f,0.f}; }

    bf16u* Pw = Ps + wave * 32 * PP;

    __syncthreads();   // drain stage(0)

    int p = 0;
    for (int jt = 0; jt < NT; ++jt) {
        bf16u* KsB = p ? buf1 : buf0;
        bf16u* VsB = KsB + (size_t)KS * 8;
        if (jt + 1 < NT) stage(jt + 1, p ? buf0 : buf1);

        // scores for both q-halves; each K fragment read feeds 2 MFMAs
        f32x4 s0[4], s1[4];
        const bool domask = ((N & 63) != 0) && (jt == NT - 1);
#pragma unroll
        for (int sub = 0; sub < 4; ++sub) {
            f32x4 a0 = {}, a1 = {};
#pragma unroll
            for (int kc = 0; kc < KC; ++kc) {
                int c = kc * 4 + quad;
                frag8 bfr = *(const frag8*)(KsB + ((size_t)((sub * 16 + mrow) * C8 + (c ^ (mrow & CM)))) * 8);
                a0 = __builtin_amdgcn_mfma_f32_16x16x32_bf16(qf0[kc], bfr, a0, 0, 0, 0);
                a1 = __builtin_amdgcn_mfma_f32_16x16x32_bf16(qf1[kc], bfr, a1, 0, 0, 0);
            }
            if (domask) {
                int col = jt * 64 + sub * 16 + mrow;
                if (col >= N) {
                    a0[0] = a0[1] = a0[2] = a0[3] = -30000.f;
                    a1[0] = a1[1] = a1[2] = a1[3] = -30000.f;
                }
            }
            s0[sub] = a0; s1[sub] = a1;
        }

        // exp2 (log2e folded into Q scale)
#pragma unroll
        for (int sub = 0; sub < 4; ++sub)
#pragma unroll
            for (int e = 0; e < 4; ++e) {
                float p0 = __builtin_amdgcn_exp2f(s0[sub][e]);
                float p1 = __builtin_amdgcn_exp2f(s1[sub][e]);
                s0[sub][e] = p0; s1[sub][e] = p1;
                lrun0[e] += p0; lrun1[e] += p1;
            }

        // P -> per-wave LDS (rows 0-15 = qh0, 16-31 = qh1)
#pragma unroll
        for (int e = 0; e < 4; ++e) {
            uint2 u0, u1;
            u0.x = pk2bf(s0[0][e], s0[1][e]);
            u0.y = pk2bf(s0[2][e], s0[3][e]);
            u1.x = pk2bf(s1[0][e], s1[1][e]);
            u1.y = pk2bf(s1[2][e], s1[3][e]);
            *(uint2*)(Pw + (quad * 4 + e) * PP + mrow * 4) = u0;
            *(uint2*)(Pw + (16 + quad * 4 + e) * PP + mrow * 4) = u1;
        }

        // PV: each V fragment read feeds 2 MFMAs
#pragma unroll
        for (int jc = 0; jc < 2; ++jc) {
            frag8 af0 = *(const frag8*)(Pw + mrow * PP + jc * 32 + quad * 8);
            frag8 af1 = *(const frag8*)(Pw + (16 + mrow) * PP + jc * 32 + quad * 8);
            int c = jc * 4 + quad;
#pragma unroll
            for (int t = 0; t < DHT; ++t) {
                frag8 bfr = *(const frag8*)(VsB + ((size_t)((t * 16 + mrow) * 8 + (c ^ (mrow & 7)))) * 8);
                oacc0[t] = __builtin_amdgcn_mfma_f32_16x16x32_bf16(af0, bfr, oacc0[t], 0, 0, 0);
                oacc1[t] = __builtin_amdgcn_mfma_f32_16x16x32_bf16(af1, bfr, oacc1[t], 0, 0, 0);
            }
        }
        __syncthreads();
        p ^= 1;
    }

    lrun0 = bfly_add16(lrun0);
    lrun1 = bfly_add16(lrun1);
    f32x4 linv0, linv1;
#pragma unroll
    for (int e = 0; e < 4; ++e) { linv0[e] = 1.0f / lrun0[e]; linv1[e] = 1.0f / lrun1[e]; }
#pragma unroll
    for (int t = 0; t < DHT; ++t) {
        int d = t * 16 + mrow;
        if (d >= DH) continue;
#pragma unroll
        for (int e = 0; e < 4; ++e) {
            int n0 = qb + wave * 32 + quad * 4 + e;
            int n1 = n0 + 16;
            if (n0 < N)
                O[((size_t)(b * N + n0)) * E + h * DH + d] = f2bf(oacc0[t][e] * linv0[e]);
            if (n1 < N)
                O[((size_t)(b * N + n1)) * E + h * DH + d] = f2bf(oacc1[t][e] * linv1[e]);
        }
    }
}

// s3 attention body (DH=96, N=49): single-tile padded-LDS path
__device__ __forceinline__ void attn_s3_body(bf16u* __restrict__ smem,
                                             const bf16u* __restrict__ Qg, const bf16u* __restrict__ Kg,
                                             const bf16u* __restrict__ Vtg, bf16u* __restrict__ Og,
                                             int lin) {
    constexpr int DH = 96, N = 49, DHP = 96, KC = 3, DHT = 6, NJc = 64, E = 768;
    constexpr int KP = 104, QP = 104, VP = 72, PP = 72, C8 = 12;
    bf16u* Ks = smem;
    bf16u* Vs = Ks + 64 * KP;
    bf16u* QsPw = Vs + DHT * 16 * VP;

    const bf16u* Q = Qg + xoff[3];
    const bf16u* K = Kg + xoff[3];
    const bf16u* Vt = Vtg + voff[3];
    bf16u* O = Og + xoff[3];

    int h = lin & 7, b = lin >> 3;
    int tid = threadIdx.x, wave = tid >> 6, lane = tid & 63;
    int mrow = lane & 15, quad = lane >> 4;

    for (int idx = tid; idx < 64 * C8; idx += 256) {
        int row = idx / C8, col = (idx % C8) * 8;
        int n = row; if (n >= N) n = N - 1;
        frag8 v = {};
        if (col < DH) v = *(const frag8*)(Q + ((size_t)(b * N + n)) * E + h * DH + col);
        *(frag8*)(QsPw + row * QP + col) = v;
    }
    for (int idx = tid; idx < 64 * C8; idx += 256) {
        int row = idx / C8, col = (idx % C8) * 8;
        int n = row; if (n >= N) n = N - 1;
        frag8 v = {};
        if (col < DH) v = *(const frag8*)(K + (size_t)(b * N + n) * E + h * DH + col);
        *(frag8*)(Ks + row * KP + col) = v;
    }
    const bf16u* Vb2 = Vt + (size_t)(b * 8 + h) * DHP * NJc;
    for (int idx = tid; idx < DHT * 16 * 8; idx += 256) {
        int d = idx / 8, j = (idx % 8) * 8;
        frag8 v = {};
        if (d < DH) v = *(const frag8*)(Vb2 + (size_t)d * NJc + j);
        *(frag8*)(Vs + d * VP + j) = v;
    }
    __syncthreads();
    frag8 qf[KC];
#pragma unroll
    for (int kc = 0; kc < KC; ++kc)
        qf[kc] = *(const frag8*)(QsPw + (wave * 16 + mrow) * QP + kc * 32 + quad * 8);
    __syncthreads();
    bf16u* Pw = QsPw + wave * 16 * PP;

    f32x4 lrun = {0.f, 0.f, 0.f, 0.f};
    f32x4 oacc[DHT];
#pragma unroll
    for (int t = 0; t < DHT; ++t) oacc[t] = f32x4{0.f, 0.f, 0.f, 0.f};

    f32x4 s[4];
#pragma unroll
    for (int sub = 0; sub < 4; ++sub) {
        f32x4 acc = {};
#pragma unroll
        for (int kc = 0; kc < KC; ++kc) {
            frag8 bfr = *(const frag8*)(Ks + (sub * 16 + mrow) * KP + kc * 32 + quad * 8);
            acc = __builtin_amdgcn_mfma_f32_16x16x32_bf16(qf[kc], bfr, acc, 0, 0, 0);
        }
        int col = sub * 16 + mrow;
        if (col >= N) { acc[0] = acc[1] = acc[2] = acc[3] = -30000.f; }
        s[sub] = acc;
    }
#pragma unroll
    for (int sub = 0; sub < 4; ++sub)
#pragma unroll
        for (int e = 0; e < 4; ++e) {
            float px = __builtin_amdgcn_exp2f(s[sub][e]);
            s[sub][e] = px;
            lrun[e] += px;
        }
#pragma unroll
    for (int e = 0; e < 4; ++e) {
        uint2 u;
        u.x = pk2bf(s[0][e], s[1][e]);
        u.y = pk2bf(s[2][e], s[3][e]);
        *(uint2*)(Pw + (quad * 4 + e) * PP + mrow * 4) = u;
    }
#pragma unroll
    for (int jc = 0; jc < 2; ++jc) {
        frag8 af = *(const frag8*)(Pw + mrow * PP + jc * 32 + quad * 8);
#pragma unroll
        for (int t = 0; t < DHT; ++t) {
            frag8 bfr = *(const frag8*)(Vs + (t * 16 + mrow) * VP + jc * 32 + quad * 8);
            oacc[t] = __builtin_amdgcn_mfma_f32_16x16x32_bf16(af, bfr, oacc[t], 0, 0, 0);
        }
    }

    lrun = bfly_add16(lrun);
    f32x4 linv;
#pragma unroll
    for (int e = 0; e < 4; ++e) linv[e] = 1.0f / lrun[e];
#pragma unroll
    for (int t = 0; t < DHT; ++t) {
        int d = t * 16 + mrow;
#pragma unroll
        for (int e = 0; e < 4; ++e) {
            int n = wave * 16 + quad * 4 + e;
            if (n < N)
                O[((size_t)(b * N + n)) * E + h * DH + d] = f2bf(oacc[t][e] * linv[e]);
        }
    }
}

// Merged attention: 0..2047 = fat (per-segment balanced XCD swizzle),
// 2048..2175 = s3 (absorbed; hides under fat tail).
__global__ __launch_bounds__(256, 3) void attn_all(const bf16u* __restrict__ Qb, const bf16u* __restrict__ Kb,
                                                   const bf16u* __restrict__ Vt, bf16u* __restrict__ Ob) {
    __shared__ __align__(16) bf16u smem[23552];   // fat: 2*896*8 + 4*32*72; s3 uses 20224
    int g = blockIdx.x;
    if (g < 896) {
        int l = (g & 7) * 112 + (g >> 3);
        attn_body3<48, 784>(smem, Qb + xoff[0], Kb + xoff[0], Vt + voff[0], Ob + xoff[0], l);
    } else if (g < 1792) {
        int gg = g - 896;
        int l = (gg & 7) * 112 + (gg >> 3);
        attn_body3<24, 784>(smem, Qb + xoff[1], Kb + xoff[1], Vt + voff[1], Ob + xoff[1], l);
    } else if (g < 2048) {
        int gg = g - 1792;
        int l = (gg & 7) * 32 + (gg >> 3);
        attn_body3<48, 196>(smem, Qb + xoff[2], Kb + xoff[2], Vt + voff[2], Ob + xoff[2], l);
    } else {
        attn_s3_body(smem, Qb, Kb, Vt, Ob, g - 2048);
    }
}

// ---------------------------------------------------------------------------
// Fused O-GEMM + unflatten + residual (round-9 dbuf version, unchanged)
// ---------------------------------------------------------------------------
template<int SC>
__device__ __forceinline__ size_t out_index(int rowg, int cg) {
    if (SC == 0) {
        int b = rowg / 784, n = rowg - b * 784;
        int slot = cg / 96, c = cg - slot * 96;
        int hh = n / 28, ww = n - hh * 28;
        return ((size_t)(b * 96 + c) * 56 + 2 * hh + (slot >> 1)) * 56 + 2 * ww + (slot & 1);
    } else if (SC == 1) {
        int b = rowg / 784, n = rowg - b * 784;
        return ((size_t)(b * 192 + cg)) * 784 + n;
    } else if (SC == 2) {
        int b = rowg / 196, n = rowg - b * 196;
        return ((size_t)(b * 384 + cg)) * 196 + n;
    } else {
        int b = rowg / 49, n = rowg - b * 49;
        return ((size_t)(b * 768 + cg)) * 49 + n;
    }
}

template<int SC>
__device__ __forceinline__ void o_tile128(const bf16u* __restrict__ A, const bf16u* __restrict__ W,
                                          const float* __restrict__ bias,
                                          const float* __restrict__ xd, float* __restrict__ out,
                                          int M, int E, int mTile, int eTile, bf16u* sm) {
    bf16u* A0 = sm;
    bf16u* B0 = sm + 4096;
    bf16u* A1 = sm + 8192;
    bf16u* B1 = sm + 12288;
    int tid = threadIdx.x, wave = tid >> 6, lane = tid & 63;
    int mbase = mTile * 128, ebase = eTile * 128;
    int wm = (wave & 1) * 64, wn = (wave >> 1) * 64;
    int mrow = lane & 15, quad = lane >> 4;
    f32x4 acc[4][4] = {};
    int srow = tid >> 2, sch = (tid & 3) * 8;
    int K = E;
    int m0 = mbase + srow;      if (m0 >= M) m0 = M - 1;
    int m1 = mbase + srow + 64; if (m1 >= M) m1 = M - 1;
    const bf16u* Ag0 = A + (size_t)m0 * K + sch;
    const bf16u* Ag1 = A + (size_t)m1 * K + sch;
    const bf16u* Wg0 = W + (size_t)(ebase + srow) * K + sch;
    const bf16u* Wg1 = W + (size_t)(ebase + srow + 64) * K + sch;
    int la = mrow * 32 + quad * 8;

    auto stage = [&](int k0, bf16u* As, bf16u* Bs) {
        async_cp16(Ag0 + k0, As + tid * 8);
        async_cp16(Ag1 + k0, As + 2048 + tid * 8);
        async_cp16(Wg0 + k0, Bs + tid * 8);
        async_cp16(Wg1 + k0, Bs + 2048 + tid * 8);
    };
    auto compute = [&](const bf16u* As, const bf16u* Bs) {
        frag8 af[4], bfr[4];
#pragma unroll
        for (int i = 0; i < 4; ++i) {
            af[i]  = *(const frag8*)(As + (wm + i * 16) * 32 + la);
            bfr[i] = *(const frag8*)(Bs + (wn + i * 16) * 32 + la);
        }
#pragma unroll
        for (int i = 0; i < 4; ++i)
#pragma unroll
            for (int j = 0; j < 4; ++j)
                acc[i][j] = __builtin_amdgcn_mfma_f32_16x16x32_bf16(af[i], bfr[j], acc[i][j], 0, 0, 0);
    };

    stage(0, A0, B0);
    __syncthreads();
    for (int k0 = 0; k0 < K; k0 += 64) {
        stage(k0 + 32, A1, B1);
        compute(A0, B0);
        __syncthreads();
        if (k0 + 64 < K) stage(k0 + 64, A0, B0);
        compute(A1, B1);
        if (k0 + 64 < K) __syncthreads();
    }

    float* Ls = (float*)sm;   // 32 x 133
#pragma unroll
    for (int ph = 0; ph < 4; ++ph) {
        __syncthreads();
        if ((wave & 1) == (ph >> 1)) {
            int mt0 = (ph & 1) * 2;
#pragma unroll
            for (int mi = 0; mi < 2; ++mi) {
                int mt = mt0 + mi;
#pragma unroll
                for (int nt = 0; nt < 4; ++nt)
#pragma unroll
                    for (int r = 0; r < 4; ++r)
                        Ls[(mi * 16 + quad * 4 + r) * 133 + wn + nt * 16 + mrow] = acc[mt][nt][r];
            }
        }
        __syncthreads();
        int rb = mbase + ph * 32;
#pragma unroll
        for (int i = 0; i < 16; ++i) {
            int coll = (tid >> 5) + i * 8;
            int l = tid & 31;
            int rg = rb + l;
            if (rg < M) {
                int cg = ebase + coll;
                size_t oi = out_index<SC>(rg, cg);
                out[oi] = xd[oi] + Ls[l * 133 + coll] + bias[cg];
            }
        }
    }
}

__device__ __forceinline__ void o_tile64_s1(const bf16u* __restrict__ A, const bf16u* __restrict__ W,
                                            const float* __restrict__ bias,
                                            const float* __restrict__ xd, float* __restrict__ out,
                                            int M, int E, int mTile, int eTile, bf16u* sm) {
    bf16u* A0 = sm;
    bf16u* B0 = sm + 2048;
    bf16u* A1 = sm + 4096;
    bf16u* B1 = sm + 6144;
    int tid = threadIdx.x, wave = tid >> 6, lane = tid & 63;
    int mbase = mTile * 64, ebase = eTile * 64;
    int wm = (wave & 1) * 32, wn = (wave >> 1) * 32;
    int mrow = lane & 15, quad = lane >> 4;
    f32x4 acc[2][2] = {};
    int srow = tid >> 2, sch = (tid & 3) * 8;
    int K = E;
    int m = mbase + srow; if (m >= M) m = M - 1;
    const bf16u* Ag = A + (size_t)m * K + sch;
    const bf16u* Wg = W + (size_t)(ebase + srow) * K + sch;
    int la = mrow * 32 + quad * 8;

    auto stage = [&](int k0, bf16u* As, bf16u* Bs) {
        async_cp16(Ag + k0, As + tid * 8);
        async_cp16(Wg + k0, Bs + tid * 8);
    };
    auto compute = [&](const bf16u* As, const bf16u* Bs) {
        frag8 af0 = *(const frag8*)(As + wm * 32 + la);
        frag8 af1 = *(const frag8*)(As + (wm + 16) * 32 + la);
        frag8 bf0 = *(const frag8*)(Bs + wn * 32 + la);
        frag8 bf1 = *(const frag8*)(Bs + (wn + 16) * 32 + la);
        acc[0][0] = __builtin_amdgcn_mfma_f32_16x16x32_bf16(af0, bf0, acc[0][0], 0, 0, 0);
        acc[0][1] = __builtin_amdgcn_mfma_f32_16x16x32_bf16(af0, bf1, acc[0][1], 0, 0, 0);
        acc[1][0] = __builtin_amdgcn_mfma_f32_16x16x32_bf16(af1, bf0, acc[1][0], 0, 0, 0);
        acc[1][1] = __builtin_amdgcn_mfma_f32_16x16x32_bf16(af1, bf1, acc[1][1], 0, 0, 0);
    };

    stage(0, A0, B0);
    __syncthreads();
    for (int k0 = 0; k0 < K; k0 += 64) {
        stage(k0 + 32, A1, B1);
        compute(A0, B0);
        __syncthreads();
        if (k0 + 64 < K) stage(k0 + 64, A0, B0);
        compute(A1, B1);
        if (k0 + 64 < K) __syncthreads();
    }

    float* Ls = (float*)sm;   // 32 x 69
#pragma unroll
    for (int ph = 0; ph < 2; ++ph) {
        __syncthreads();
        if ((wave & 1) == ph) {
#pragma unroll
            for (int mt = 0; mt < 2; ++mt)
#pragma unroll
                for (int nt = 0; nt < 2; ++nt)
#pragma unroll
                    for (int r = 0; r < 4; ++r)
                        Ls[(mt * 16 + quad * 4 + r) * 69 + wn + nt * 16 + mrow] = acc[mt][nt][r];
        }
        __syncthreads();
        int rb = mbase + ph * 32;
#pragma unroll
        for (int i = 0; i < 8; ++i) {
            int coll = (tid >> 5) + i * 8;
            int l = tid & 31;
            int rg = rb + l;
            if (rg < M) {
                int cg = ebase + coll;
                size_t oi = out_index<1>(rg, cg);
                out[oi] = xd[oi] + Ls[l * 69 + coll] + bias[cg];
            }
        }
    }
}

__global__ __launch_bounds__(256) void ounf_fat(const bf16u* __restrict__ Ob, const bf16u* __restrict__ Wb,
                                                float* __restrict__ out, BiasP bp, OunfP up) {
    __shared__ __align__(16) bf16u sm[16384];   // 2 x (As+Bs); epilogue reuses as fp32 Ls
    int blk = blockIdx.x;
    int seg = 0;
    while (seg < 3 && blk >= oStart[seg + 1]) seg++;
    int t = blk - oStart[seg];
    if (seg < 3) {
        int s = (seg == 0) ? 0 : (seg == 1 ? 2 : 3);
        int E = cE[s], M = cM[s];
        int ct = E >> 7;
        int mTile = t / ct, eTile = t - mTile * ct;
        const bf16u* A = Ob + xoff[s];
        const bf16u* W = Wb + woff[s] + (size_t)3 * E * E;
        if (s == 0)
            o_tile128<0>(A, W, bp.p[3], up.xd[0], out + xoff[0], M, E, mTile, eTile, sm);
        else if (s == 2)
            o_tile128<2>(A, W, bp.p[11], up.xd[2], out + xoff[2], M, E, mTile, eTile, sm);
        else
            o_tile128<3>(A, W, bp.p[15], up.xd[3], out + xoff[3], M, E, mTile, eTile, sm);
    } else {
        int E = 192, M = 12544;
        int mTile = t / 3, eTile = t - mTile * 3;
        o_tile64_s1(Ob + xoff[1], Wb + woff[1] + (size_t)3 * E * E, bp.p[7],
                    up.xd[1], out + xoff[1], M, E, mTile, eTile, sm);
    }
}

// ---------------------------------------------------------------------------
// Host launch — 4 dispatches
// ---------------------------------------------------------------------------
extern "C" void kernel_launch(void* const* d_in, const int* in_sizes, int n_in,
                              void* d_out, int out_size, void* d_ws, size_t ws_size,
                              hipStream_t stream) {
    bf16u* ws = (bf16u*)d_ws;
    bf16u* Qb = ws;
    bf16u* Kb = ws + 9031680;
    bf16u* Vt = ws + 18063360;
    bf16u* Ob = ws + 31170560;
    bf16u* Wb = ws + 40202240;
    bf16u* Xd = ws + 43888640;
    bf16u* Xc = ws + 52920320;
    float* out = (float*)d_out;

    PrepP pp; BiasP bb; OunfP ux;
    for (int s = 0; s < 4; ++s) {
        pp.x[s * 2]     = (const float*)d_in[s * 2];
        pp.x[s * 2 + 1] = (const float*)d_in[s * 2 + 1];
        ux.xd[s]        = (const float*)d_in[s * 2];
        int w0 = 8 + s * 8;
        pp.w[s * 4 + 0] = (const float*)d_in[w0 + 0];
        pp.w[s * 4 + 1] = (const float*)d_in[w0 + 2];
        pp.w[s * 4 + 2] = (const float*)d_in[w0 + 4];
        pp.w[s * 4 + 3] = (const float*)d_in[w0 + 6];
        bb.p[s * 4 + 0] = (const float*)d_in[w0 + 1];
        bb.p[s * 4 + 1] = (const float*)d_in[w0 + 3];
        bb.p[s * 4 + 2] = (const float*)d_in[w0 + 5];
        bb.p[s * 4 + 3] = (const float*)d_in[w0 + 7];
    }

    prep<<<20424, 256, 0, stream>>>(pp, Xd, Xc, Wb);
    qkv_all<<<2802, 256, 0, stream>>>(Xd, Xc, Wb, Qb, Kb, Vt, bb);
    attn_all<<<2176, 256, 0, stream>>>(Qb, Kb, Vt, Ob);
    ounf_fat<<<999, 256, 0, stream>>>(Ob, Wb, out, bb, ux);
}

// Round 12
// 353.354 us; speedup vs baseline: 1.0318x; 1.0318x over previous
//
#include <hip/hip_runtime.h>
#include <hip/hip_bf16.h>
#include <cstdint>
#include <cstddef>
#include <cmath>

typedef unsigned short bf16u;
typedef float f32x4 __attribute__((ext_vector_type(4)));
typedef short frag8 __attribute__((ext_vector_type(8)));

typedef __attribute__((address_space(1))) uint32_t u32g;
typedef __attribute__((address_space(3))) uint32_t u32l;

__device__ __forceinline__ void async_cp16(const bf16u* g, bf16u* l) {
    __builtin_amdgcn_global_load_lds((u32g*)g, (u32l*)l, 16, 0, 0);
}

__device__ __forceinline__ bf16u f2bf(float f) {
    union { float f; uint32_t u; } v; v.f = f;
    uint32_t u = v.u;
    return (bf16u)((u + 0x7fffu + ((u >> 16) & 1u)) >> 16);   // RNE
}

__device__ __forceinline__ uint32_t pk2bf(float a, float b) {
    __hip_bfloat162 h = __float22bfloat162_rn(make_float2(a, b));  // v_cvt_pk_bf16_f32
    union { __hip_bfloat162 h; uint32_t u; } c; c.h = h; return c.u;
}

// key permutation within each 64-block of the key axis: slot = (k&15)*4 + (k>>4)&3
__device__ __forceinline__ int vperm(int n) {
    return (n & ~63) | ((n & 15) << 2) | ((n >> 4) & 3);
}

// ---------------------------------------------------------------------------
// Compile-time tables (4 scales)
// ---------------------------------------------------------------------------
static constexpr int cN[4]   = {784, 784, 196, 49};
static constexpr int cE[4]   = {384, 192, 384, 768};
static constexpr int cM[4]   = {12544, 12544, 3136, 784};
static constexpr int cC[4]   = {96, 192, 384, 768};
static constexpr int cH[4]   = {56, 28, 14, 7};
static constexpr int cS[4]   = {2, 1, 1, 1};
static constexpr int cWt[4]  = {28, 28, 14, 7};

static constexpr size_t xoff[4] = {0, 4816896, 7225344, 8429568};   // M*E cumsum (also out offs)
static constexpr size_t voff[4] = {0, 6815744, 10223616, 12320768}; // 128*DHP*NJ cumsum
static constexpr size_t woff[4] = {0, 589824, 737280, 1327104};     // 4*E^2 cumsum

// scale * log2(e)  (exp2-domain softmax)
__device__ __constant__ float qsc[4] = {0.20823509f, 0.29448888f, 0.20823509f, 0.14724444f};

// HALF-M tile counts (64-row tiles, 128-col panels):
// s0: 196x3=588, s2: 49x3=147, s3: 13x6=78, s1(64x64): 196x3=588
static constexpr int hStart[5] = {0, 588, 735, 813, 1401};
// ounf union: s0(128,294), s2(128,75), s3(128,42), s1(64,588)
static constexpr int oStart[5]  = {0,294,369,411,999};

static constexpr int fStart[9] = {0,4800,9600,12000,14400,15744,17088,17856,18624};
static constexpr int wCum[17]  = {0,72,144,216,288,306,324,342,360,432,504,576,648,936,1224,1512,1800};
static constexpr int fNtn[4] = {25, 25, 7, 2};
static constexpr int fNtc[4] = {3, 6, 12, 24};
static constexpr int fSp[4]  = {4, 1, 1, 1};

struct BiasP { const float* p[16]; };
struct PrepP { const float* x[8]; const float* w[16]; };
struct OunfP { const float* xd[4]; };

// ---------------------------------------------------------------------------
// prep: 8 flatten-transposes (fp32 -> bf16) + 16 weight converts (unchanged)
// ---------------------------------------------------------------------------
__global__ __launch_bounds__(256) void prep(PrepP pp, bf16u* __restrict__ Xd,
                                            bf16u* __restrict__ Xc, bf16u* __restrict__ Wb) {
    int blk = blockIdx.x, tid = threadIdx.x;
    if (blk < 18624) {
        __shared__ float tile[32][33];
        int seg = 0;
        while (seg < 7 && blk >= fStart[seg + 1]) seg++;
        int s = seg >> 1, which = seg & 1;
        int l = blk - fStart[seg];
        int ntn = fNtn[s], ntc = fNtc[s], sp = fSp[s];
        int nt = l % ntn; l /= ntn;
        int ctl = l % ntc; l /= ntc;
        int spi = l % sp; int b = l / sp;
        int sv = cS[s];
        int s1i = spi / sv, s2i = spi % sv;
        int C = cC[s], H = cH[s], Wd = cH[s], N = cN[s], E2 = cE[s], Wt = cWt[s];
        const float* x = pp.x[s * 2 + which];
        bf16u* dst = (which ? Xc : Xd) + xoff[s];
        int tx = tid & 31, ty = tid >> 5;
        int n0 = nt * 32, c0 = ctl * 32;
#pragma unroll
        for (int rr = 0; rr < 4; ++rr) {
            int c = c0 + rr * 8 + ty;
            int n = n0 + tx;
            if (n < N) {
                int hh = (n / Wt) * sv + s1i;
                int ww = (n % Wt) * sv + s2i;
                tile[rr * 8 + ty][tx] = x[((size_t)(b * C + c) * H + hh) * Wd + ww];
            }
        }
        __syncthreads();
        int ebase = (s1i * sv + s2i) * C + c0;
#pragma unroll
        for (int rr = 0; rr < 4; ++rr) {
            int n = n0 + rr * 8 + ty;
            if (n < N)
                dst[((size_t)b * N + n) * E2 + ebase + tx] = f2bf(tile[tx][rr * 8 + ty]);
        }
    } else {
        int wb = blk - 18624;
        int m2 = 0;
        while (m2 < 15 && wb >= wCum[m2 + 1]) m2++;
        int s = m2 >> 2, mi = m2 & 3;
        size_t e2 = (size_t)cE[s] * cE[s];
        size_t base = (size_t)(wb - wCum[m2]) * 2048 + tid * 8;
        const float* src = pp.w[m2];
        bf16u* dst = Wb + woff[s] + mi * e2 + base;
        float4 a = *(const float4*)(src + base);
        float4 c = *(const float4*)(src + base + 4);
        bf16u o[8] = {f2bf(a.x), f2bf(a.y), f2bf(a.z), f2bf(a.w),
                      f2bf(c.x), f2bf(c.y), f2bf(c.z), f2bf(c.w)};
        *(frag8*)dst = *(frag8*)o;
    }
}

// ---------------------------------------------------------------------------
// HALF-M Q tile: 64 rows x 128 cols, single-buffered. (round-11, unchanged)
// ---------------------------------------------------------------------------
__device__ __forceinline__ void gemm_q_h(const bf16u* __restrict__ A, const bf16u* __restrict__ W,
                                         const float* __restrict__ bias,
                                         int M, int E, int mTile, int eTile, float oscale,
                                         bf16u* __restrict__ outB, bf16u* sm) {
    bf16u* As = sm;          // 64 x 32
    bf16u* Bs = sm + 2048;   // 128 x 32
    int tid = threadIdx.x, wave = tid >> 6, lane = tid & 63;
    int mbase = mTile * 64, ebase = eTile * 128;
    int wm = (wave & 1) * 32, wn = (wave >> 1) * 64;
    f32x4 acc[2][4] = {};
    int srow = tid >> 2, sch = (tid & 3) * 8;
    int K = E;
    int m = mbase + srow; if (m >= M) m = M - 1;
    const bf16u* Ag  = A + (size_t)m * K + sch;
    const bf16u* Wg0 = W + (size_t)(ebase + srow) * K + sch;
    const bf16u* Wg1 = W + (size_t)(ebase + srow + 64) * K + sch;
    int la = (lane & 15) * 32 + (lane >> 4) * 8;

    for (int k0 = 0; k0 < K; k0 += 32) {
        async_cp16(Ag + k0, As + tid * 8);
        async_cp16(Wg0 + k0, Bs + tid * 8);
        async_cp16(Wg1 + k0, Bs + 2048 + tid * 8);
        __syncthreads();
        frag8 af[2], bfr[4];
#pragma unroll
        for (int i = 0; i < 2; ++i)
            af[i] = *(const frag8*)(As + (wm + i * 16) * 32 + la);
#pragma unroll
        for (int j = 0; j < 4; ++j)
            bfr[j] = *(const frag8*)(Bs + (wn + j * 16) * 32 + la);
#pragma unroll
        for (int i = 0; i < 2; ++i)
#pragma unroll
            for (int j = 0; j < 4; ++j)
                acc[i][j] = __builtin_amdgcn_mfma_f32_16x16x32_bf16(af[i], bfr[j], acc[i][j], 0, 0, 0);
        __syncthreads();
    }

    int mrow = lane & 15, quad = lane >> 4;
#pragma unroll
    for (int mt = 0; mt < 2; ++mt) {
#pragma unroll
        for (int nt = 0; nt < 4; ++nt) {
            int col = ebase + wn + nt * 16 + mrow;
            float bv = bias[col];
            int rbase = mbase + wm + mt * 16 + quad * 4;
#pragma unroll
            for (int r = 0; r < 4; ++r) {
                int rowg = rbase + r;
                if (rowg >= M) continue;
                outB[(size_t)rowg * E + col] = f2bf((acc[mt][nt][r] + bv) * oscale);
            }
        }
    }
}

// ---------------------------------------------------------------------------
// HALF-M fused K+V tile: 64 rows x 128 cols, single-buffered.
// NEW (round-12): V epilogue transposed through LDS so each store
// instruction's 64 lanes land in ONE vperm 64-slot block (2-3 cache lines
// vs 16 before) — kills the V write amplification (round-11 diagnosis:
// qkv time = bytes / 2.5 TB/s; WRITE was 1.7x ideal).
// LDS: A 2048 + K 4096 + V 4096 = 10240 elems; epilogue reuses as 128x66.
// ---------------------------------------------------------------------------
template<int NN, int DHt, int DHPt, int NJt>
__device__ __forceinline__ void gemm_kv_h(const bf16u* __restrict__ A, const bf16u* __restrict__ Wk,
                                          const bf16u* __restrict__ Wv,
                                          const float* __restrict__ bk, const float* __restrict__ bv,
                                          int M, int E, int mTile, int eTile,
                                          bf16u* __restrict__ Ko, bf16u* __restrict__ Vo, bf16u* sm) {
    bf16u* As = sm;          // 64 x 32
    bf16u* Ks = sm + 2048;   // 128 x 32
    bf16u* Vs = sm + 6144;   // 128 x 32
    int tid = threadIdx.x, wave = tid >> 6, lane = tid & 63;
    int mbase = mTile * 64, ebase = eTile * 128;
    int wm = (wave & 1) * 32, wn = (wave >> 1) * 64;
    f32x4 acck[2][4] = {};
    f32x4 accv[2][4] = {};
    int srow = tid >> 2, sch = (tid & 3) * 8;
    int Kd = E;
    int m = mbase + srow; if (m >= M) m = M - 1;
    const bf16u* Ag  = A + (size_t)m * Kd + sch;
    const bf16u* Kg0 = Wk + (size_t)(ebase + srow) * Kd + sch;
    const bf16u* Kg1 = Wk + (size_t)(ebase + srow + 64) * Kd + sch;
    const bf16u* Vg0 = Wv + (size_t)(ebase + srow) * Kd + sch;
    const bf16u* Vg1 = Wv + (size_t)(ebase + srow + 64) * Kd + sch;
    int la = (lane & 15) * 32 + (lane >> 4) * 8;

    for (int k0 = 0; k0 < Kd; k0 += 32) {
        async_cp16(Ag + k0, As + tid * 8);
        async_cp16(Kg0 + k0, Ks + tid * 8);
        async_cp16(Kg1 + k0, Ks + 2048 + tid * 8);
        async_cp16(Vg0 + k0, Vs + tid * 8);
        async_cp16(Vg1 + k0, Vs + 2048 + tid * 8);
        __syncthreads();
        frag8 af[2], bfr[4];
#pragma unroll
        for (int i = 0; i < 2; ++i)
            af[i] = *(const frag8*)(As + (wm + i * 16) * 32 + la);
#pragma unroll
        for (int j = 0; j < 4; ++j)
            bfr[j] = *(const frag8*)(Ks + (wn + j * 16) * 32 + la);
#pragma unroll
        for (int i = 0; i < 2; ++i)
#pragma unroll
            for (int j = 0; j < 4; ++j)
                acck[i][j] = __builtin_amdgcn_mfma_f32_16x16x32_bf16(af[i], bfr[j], acck[i][j], 0, 0, 0);
#pragma unroll
        for (int j = 0; j < 4; ++j)
            bfr[j] = *(const frag8*)(Vs + (wn + j * 16) * 32 + la);
#pragma unroll
        for (int i = 0; i < 2; ++i)
#pragma unroll
            for (int j = 0; j < 4; ++j)
                accv[i][j] = __builtin_amdgcn_mfma_f32_16x16x32_bf16(af[i], bfr[j], accv[i][j], 0, 0, 0);
        __syncthreads();
    }

    int mrow = lane & 15, quad = lane >> 4;
    // K epilogue (row-major, already line-friendly)
#pragma unroll
    for (int mt = 0; mt < 2; ++mt) {
#pragma unroll
        for (int nt = 0; nt < 4; ++nt) {
            int col = ebase + wn + nt * 16 + mrow;
            float bkc = bk[col];
            int rbase = mbase + wm + mt * 16 + quad * 4;
#pragma unroll
            for (int r = 0; r < 4; ++r) {
                int rowg = rbase + r;
                if (rowg >= M) continue;
                Ko[(size_t)rowg * E + col] = f2bf(acck[mt][nt][r] + bkc);
            }
        }
    }

    // V epilogue: stage transposed [colLocal][rowLocal] in LDS (stride 66),
    // then lane=row walk -> each instruction's lanes hit one vperm block.
    bf16u* vt = sm;   // safe: K-loop ended with __syncthreads()
#pragma unroll
    for (int mt = 0; mt < 2; ++mt) {
#pragma unroll
        for (int nt = 0; nt < 4; ++nt) {
            int cl = wn + nt * 16 + mrow;
            float bvc = bv[ebase + cl];
            int rl0 = wm + mt * 16 + quad * 4;
#pragma unroll
            for (int r = 0; r < 4; ++r)
                vt[cl * 66 + rl0 + r] = f2bf(accv[mt][nt][r] + bvc);
        }
    }
    __syncthreads();
    {
        int rowg = mbase + lane;
        bool ok = rowg < M;
        int b2 = rowg / NN, n = rowg - b2 * NN;
        int vp = vperm(n);
        int c0 = wave * 32;
#pragma unroll
        for (int ci = 0; ci < 32; ++ci) {
            int c = c0 + ci;
            int colg = ebase + c;
            int hh = colg / DHt, d = colg - hh * DHt;
            if (ok)
                Vo[((size_t)(b2 * 8 + hh) * DHPt + d) * NJt + vp] = vt[c * 66 + lane];
        }
    }
}

// ---------------------------------------------------------------------------
// s1 (E=192) 64x64 Q tile, single-buffered (unchanged)
// ---------------------------------------------------------------------------
__device__ __forceinline__ void gemm_q64_s1(const bf16u* __restrict__ A, const bf16u* __restrict__ W,
                                            const float* __restrict__ bias,
                                            int M, int E, int mTile, int eTile, float oscale,
                                            bf16u* __restrict__ outB, bf16u* sm) {
    bf16u* As = sm;
    bf16u* Bs = sm + 2048;
    int tid = threadIdx.x, wave = tid >> 6, lane = tid & 63;
    int mbase = mTile * 64, ebase = eTile * 64;
    int wm = (wave & 1) * 32, wn = (wave >> 1) * 32;
    f32x4 acc[2][2] = {};
    int srow = tid >> 2, sch = (tid & 3) * 8;
    int K = E;
    int m = mbase + srow; if (m >= M) m = M - 1;
    const bf16u* Ag = A + (size_t)m * K + sch;
    const bf16u* Wg = W + (size_t)(ebase + srow) * K + sch;
    int la = (lane & 15) * 32 + (lane >> 4) * 8;

    for (int k0 = 0; k0 < K; k0 += 32) {
        async_cp16(Ag + k0, As + tid * 8);
        async_cp16(Wg + k0, Bs + tid * 8);
        __syncthreads();
        frag8 af0 = *(const frag8*)(As + wm * 32 + la);
        frag8 af1 = *(const frag8*)(As + (wm + 16) * 32 + la);
        frag8 bf0 = *(const frag8*)(Bs + wn * 32 + la);
        frag8 bf1 = *(const frag8*)(Bs + (wn + 16) * 32 + la);
        acc[0][0] = __builtin_amdgcn_mfma_f32_16x16x32_bf16(af0, bf0, acc[0][0], 0, 0, 0);
        acc[0][1] = __builtin_amdgcn_mfma_f32_16x16x32_bf16(af0, bf1, acc[0][1], 0, 0, 0);
        acc[1][0] = __builtin_amdgcn_mfma_f32_16x16x32_bf16(af1, bf0, acc[1][0], 0, 0, 0);
        acc[1][1] = __builtin_amdgcn_mfma_f32_16x16x32_bf16(af1, bf1, acc[1][1], 0, 0, 0);
        __syncthreads();
    }

    int mrow = lane & 15, quad = lane >> 4;
#pragma unroll
    for (int mt = 0; mt < 2; ++mt) {
#pragma unroll
        for (int nt = 0; nt < 2; ++nt) {
            int col = ebase + wn + nt * 16 + mrow;
            float bv = bias[col];
            int rbase = mbase + wm + mt * 16 + quad * 4;
#pragma unroll
            for (int r = 0; r < 4; ++r) {
                int rowg = rbase + r;
                if (rowg >= M) continue;
                outB[(size_t)rowg * E + col] = f2bf((acc[mt][nt][r] + bv) * oscale);
            }
        }
    }
}

// ---------------------------------------------------------------------------
// s1 fused K+V 64x64 tile, single-buffered, with LDS-coalesced V epilogue
// ---------------------------------------------------------------------------
template<int NN, int DHt, int DHPt, int NJt>
__device__ __forceinline__ void gemm_kv64(const bf16u* __restrict__ A, const bf16u* __restrict__ Wk,
                                          const bf16u* __restrict__ Wv,
                                          const float* __restrict__ bk, const float* __restrict__ bv,
                                          int M, int E, int mTile, int eTile,
                                          bf16u* __restrict__ Ko, bf16u* __restrict__ Vo, bf16u* sm) {
    bf16u* As = sm;
    bf16u* Ks = sm + 2048;
    bf16u* Vs = sm + 4096;
    int tid = threadIdx.x, wave = tid >> 6, lane = tid & 63;
    int mbase = mTile * 64, ebase = eTile * 64;
    int wm = (wave & 1) * 32, wn = (wave >> 1) * 32;
    f32x4 acck[2][2] = {};
    f32x4 accv[2][2] = {};
    int srow = tid >> 2, sch = (tid & 3) * 8;
    int Kd = E;
    int m = mbase + srow; if (m >= M) m = M - 1;
    const bf16u* Ag = A + (size_t)m * Kd + sch;
    const bf16u* Kg = Wk + (size_t)(ebase + srow) * Kd + sch;
    const bf16u* Vg = Wv + (size_t)(ebase + srow) * Kd + sch;
    int la = (lane & 15) * 32 + (lane >> 4) * 8;

    for (int k0 = 0; k0 < Kd; k0 += 32) {
        async_cp16(Ag + k0, As + tid * 8);
        async_cp16(Kg + k0, Ks + tid * 8);
        async_cp16(Vg + k0, Vs + tid * 8);
        __syncthreads();
        frag8 af0 = *(const frag8*)(As + wm * 32 + la);
        frag8 af1 = *(const frag8*)(As + (wm + 16) * 32 + la);
        frag8 k0f = *(const frag8*)(Ks + wn * 32 + la);
        frag8 k1f = *(const frag8*)(Ks + (wn + 16) * 32 + la);
        acck[0][0] = __builtin_amdgcn_mfma_f32_16x16x32_bf16(af0, k0f, acck[0][0], 0, 0, 0);
        acck[0][1] = __builtin_amdgcn_mfma_f32_16x16x32_bf16(af0, k1f, acck[0][1], 0, 0, 0);
        acck[1][0] = __builtin_amdgcn_mfma_f32_16x16x32_bf16(af1, k0f, acck[1][0], 0, 0, 0);
        acck[1][1] = __builtin_amdgcn_mfma_f32_16x16x32_bf16(af1, k1f, acck[1][1], 0, 0, 0);
        frag8 v0f = *(const frag8*)(Vs + wn * 32 + la);
        frag8 v1f = *(const frag8*)(Vs + (wn + 16) * 32 + la);
        accv[0][0] = __builtin_amdgcn_mfma_f32_16x16x32_bf16(af0, v0f, accv[0][0], 0, 0, 0);
        accv[0][1] = __builtin_amdgcn_mfma_f32_16x16x32_bf16(af0, v1f, accv[0][1], 0, 0, 0);
        accv[1][0] = __builtin_amdgcn_mfma_f32_16x16x32_bf16(af1, v0f, accv[1][0], 0, 0, 0);
        accv[1][1] = __builtin_amdgcn_mfma_f32_16x16x32_bf16(af1, v1f, accv[1][1], 0, 0, 0);
        __syncthreads();
    }

    int mrow = lane & 15, quad = lane >> 4;
    // K epilogue
#pragma unroll
    for (int mt = 0; mt < 2; ++mt) {
#pragma unroll
        for (int nt = 0; nt < 2; ++nt) {
            int col = ebase + wn + nt * 16 + mrow;
            float bkc = bk[col];
            int rbase = mbase + wm + mt * 16 + quad * 4;
#pragma unroll
            for (int r = 0; r < 4; ++r) {
                int rowg = rbase + r;
                if (rowg >= M) continue;
                Ko[(size_t)rowg * E + col] = f2bf(acck[mt][nt][r] + bkc);
            }
        }
    }

    // V epilogue via LDS transpose (64 cols x 64 rows, stride 66)
    bf16u* vt = sm;
#pragma unroll
    for (int mt = 0; mt < 2; ++mt) {
#pragma unroll
        for (int nt = 0; nt < 2; ++nt) {
            int cl = wn + nt * 16 + mrow;
            float bvc = bv[ebase + cl];
            int rl0 = wm + mt * 16 + quad * 4;
#pragma unroll
            for (int r = 0; r < 4; ++r)
                vt[cl * 66 + rl0 + r] = f2bf(accv[mt][nt][r] + bvc);
        }
    }
    __syncthreads();
    {
        int rowg = mbase + lane;
        bool ok = rowg < M;
        int b2 = rowg / NN, n = rowg - b2 * NN;
        int vp = vperm(n);
        int c0 = wave * 16;
#pragma unroll
        for (int ci = 0; ci < 16; ++ci) {
            int c = c0 + ci;
            int colg = ebase + c;
            int hh = colg / DHt, d = colg - hh * DHt;
            if (ok)
                Vo[((size_t)(b2 * 8 + hh) * DHPt + d) * NJt + vp] = vt[c * 66 + lane];
        }
    }
}

// ---------------------------------------------------------------------------
// MERGED QKV, half-M tiles: blocks 0..1400 = K+V, 1401..2801 = Q.
// ---------------------------------------------------------------------------
__global__ __launch_bounds__(256, 4) void qkv_all(const bf16u* __restrict__ Xd, const bf16u* __restrict__ Xc,
                                                  const bf16u* __restrict__ Wb,
                                                  bf16u* __restrict__ Qb, bf16u* __restrict__ Kb,
                                                  bf16u* __restrict__ Vt, BiasP bp) {
    __shared__ __align__(16) bf16u sm[10240];   // 20KB; kv_h epilogue reuses as 128x66
    int blk0 = blockIdx.x;
    if (blk0 < 1401) {
        // ---- K+V path ----
        int blk = blk0;
        int seg = 0;
        while (seg < 3 && blk >= hStart[seg + 1]) seg++;
        int t = blk - hStart[seg];
        if (seg < 3) {
            int s = (seg == 0) ? 0 : (seg == 1 ? 2 : 3);
            int E = cE[s], M = cM[s];
            int ct = E >> 7;
            int mTile = t / ct, eTile = t - mTile * ct;
            const bf16u* A  = Xd + xoff[s];
            const bf16u* Wk = Wb + woff[s] + (size_t)1 * E * E;
            const bf16u* Wv = Wb + woff[s] + (size_t)2 * E * E;
            if (s == 0)
                gemm_kv_h<784, 48, 64, 832>(A, Wk, Wv, bp.p[1], bp.p[2], M, E, mTile, eTile,
                                            Kb + xoff[0], Vt + voff[0], sm);
            else if (s == 2)
                gemm_kv_h<196, 48, 64, 256>(A, Wk, Wv, bp.p[9], bp.p[10], M, E, mTile, eTile,
                                            Kb + xoff[2], Vt + voff[2], sm);
            else
                gemm_kv_h<49, 96, 96, 64>(A, Wk, Wv, bp.p[13], bp.p[14], M, E, mTile, eTile,
                                          Kb + xoff[3], Vt + voff[3], sm);
        } else {
            int E = 192, M = 12544;
            int mTile = t / 3, eTile = t - mTile * 3;
            gemm_kv64<784, 24, 32, 832>(Xd + xoff[1], Wb + woff[1] + (size_t)1 * E * E,
                                        Wb + woff[1] + (size_t)2 * E * E, bp.p[5], bp.p[6],
                                        M, E, mTile, eTile, Kb + xoff[1], Vt + voff[1], sm);
        }
    } else {
        // ---- Q path ----
        int blk = blk0 - 1401;
        int seg = 0;
        while (seg < 3 && blk >= hStart[seg + 1]) seg++;
        int t = blk - hStart[seg];
        if (seg < 3) {
            int s = (seg == 0) ? 0 : (seg == 1 ? 2 : 3);
            int E = cE[s], M = cM[s];
            int ct = E >> 7;
            int mTile = t / ct, eTile = t - mTile * ct;
            gemm_q_h(Xc + xoff[s], Wb + woff[s], bp.p[s * 4], M, E, mTile, eTile,
                     qsc[s], Qb + xoff[s], sm);
        } else {
            int E = 192, M = 12544;
            int mTile = t / 3, eTile = t - mTile * 3;
            gemm_q64_s1(Xc + xoff[1], Wb + woff[1], bp.p[4], M, E, mTile, eTile,
                        qsc[1], Qb + xoff[1], sm);
        }
    }
}

// ---------------------------------------------------------------------------
// Flash attention v3 (Q-tile 128, two 16-row frags/wave) + merged s3 path.
// (Unchanged)
// ---------------------------------------------------------------------------
__device__ __forceinline__ f32x4 bfly_add16(f32x4 v) {
#pragma unroll
    for (int m = 1; m <= 8; m <<= 1) {
        f32x4 o;
#pragma unroll
        for (int e = 0; e < 4; ++e) o[e] = __shfl_xor(v[e], m);
#pragma unroll
        for (int e = 0; e < 4; ++e) v[e] += o[e];
    }
    return v;
}

template<int DH, int N>
__device__ __forceinline__ void attn_body3(bf16u* __restrict__ smem,
                                           const bf16u* __restrict__ Q, const bf16u* __restrict__ K,
                                           const bf16u* __restrict__ Vt, bf16u* __restrict__ O,
                                           int lin) {
    constexpr int DHP = (DH == 24) ? 32 : 64;
    constexpr int C8  = DHP / 8;            // 4 or 8
    constexpr int CM  = C8 - 1;
    constexpr int KC  = DHP / 32;           // 1 or 2
    constexpr int DHT = (DH + 15) / 16;     // 2 or 3
    constexpr int VR  = DHT * 16;           // 32 or 48
    constexpr int NT  = (N + 63) / 64;      // KV tiles
    constexpr int QT  = (N + 127) / 128;    // Q tiles (128 rows/block)
    constexpr int NJc = NT * 64;
    constexpr int E   = DH * 8;
    constexpr int KS  = 64 * C8;            // 16B slots for K tile
    constexpr int TS  = KS + VR * 8;        // + V slots
    constexpr int RND = (TS + 255) / 256;
    constexpr int PP  = 72;

    bf16u* buf0 = smem;
    bf16u* buf1 = smem + (size_t)TS * 8;
    bf16u* Ps   = smem + (size_t)2 * TS * 8;

    const int qt = lin % QT;
    const int r2 = lin / QT;
    const int h = r2 & 7, b = r2 >> 3;
    const int qb = qt * 128;
    const int tid = threadIdx.x, wave = tid >> 6, lane = tid & 63;
    const int mrow = lane & 15, quad = lane >> 4;

    const bf16u* Kb2 = K + (size_t)b * N * E + h * DH;
    const bf16u* Vb2 = Vt + (size_t)(b * 8 + h) * DHP * NJc;

    auto stage = [&](int jt, bf16u* buf) {
#pragma unroll
        for (int r = 0; r < RND; ++r) {
            int s = tid + r * 256;
            bf16u* dst = buf + (size_t)s * 8;
            if (s < KS) {
                int row = s / C8;
                int cl = (s & CM) ^ (row & CM);
                int n = jt * 64 + row; if (n >= N) n = N - 1;
                async_cp16(Kb2 + (size_t)n * E + cl * 8, dst);
            } else if (s < TS) {
                int v = s - KS;
                int d = v >> 3;
                int cl = (v & 7) ^ (d & 7);
                async_cp16(Vb2 + (size_t)d * NJc + jt * 64 + cl * 8, dst);
            }
        }
    };

    stage(0, buf0);

    // Q fragments (two 16-row halves per wave), pre-scaled by scale*log2e
    frag8 qf0[KC], qf1[KC];
    {
        int qn0 = qb + wave * 32 + mrow;      if (qn0 >= N) qn0 = N - 1;
        int qn1 = qb + wave * 32 + 16 + mrow; if (qn1 >= N) qn1 = N - 1;
        const bf16u* qp0 = Q + (size_t)(b * N + qn0) * E + h * DH;
        const bf16u* qp1 = Q + (size_t)(b * N + qn1) * E + h * DH;
#pragma unroll
        for (int kc = 0; kc < KC; ++kc) {
            int col = kc * 32 + quad * 8;
            frag8 v0 = {}, v1 = {};
            if (col < DH) { v0 = *(const frag8*)(qp0 + col); v1 = *(const frag8*)(qp1 + col); }
            qf0[kc] = v0; qf1[kc] = v1;
        }
    }

    f32x4 lrun0 = {0.f, 0.f, 0.f, 0.f};
    f32x4 lrun1 = {0.f, 0.f, 0.f, 0.f};
    f32x4 oacc0[DHT], oacc1[DHT];
#pragma unroll
    for (int t = 0; t < DHT; ++t) { oacc0[t] = f32x4{0.f,0.f,0.f,0.f}; oacc1[t] = f32x4{0.f,0.f,0.f,0.f}; }

    bf16u* Pw = Ps + wave * 32 * PP;

    __syncthreads();   // drain stage(0)

    int p = 0;
    for (int jt = 0; jt < NT; ++jt) {
        bf16u* KsB = p ? buf1 : buf0;
        bf16u* VsB = KsB + (size_t)KS * 8;
        if (jt + 1 < NT) stage(jt + 1, p ? buf0 : buf1);

        // scores for both q-halves; each K fragment read feeds 2 MFMAs
        f32x4 s0[4], s1[4];
        const bool domask = ((N & 63) != 0) && (jt == NT - 1);
#pragma unroll
        for (int sub = 0; sub < 4; ++sub) {
            f32x4 a0 = {}, a1 = {};
#pragma unroll
            for (int kc = 0; kc < KC; ++kc) {
                int c = kc * 4 + quad;
                frag8 bfr = *(const frag8*)(KsB + ((size_t)((sub * 16 + mrow) * C8 + (c ^ (mrow & CM)))) * 8);
                a0 = __builtin_amdgcn_mfma_f32_16x16x32_bf16(qf0[kc], bfr, a0, 0, 0, 0);
                a1 = __builtin_amdgcn_mfma_f32_16x16x32_bf16(qf1[kc], bfr, a1, 0, 0, 0);
            }
            if (domask) {
                int col = jt * 64 + sub * 16 + mrow;
                if (col >= N) {
                    a0[0] = a0[1] = a0[2] = a0[3] = -30000.f;
                    a1[0] = a1[1] = a1[2] = a1[3] = -30000.f;
                }
            }
            s0[sub] = a0; s1[sub] = a1;
        }

        // exp2 (log2e folded into Q scale)
#pragma unroll
        for (int sub = 0; sub < 4; ++sub)
#pragma unroll
            for (int e = 0; e < 4; ++e) {
                float p0 = __builtin_amdgcn_exp2f(s0[sub][e]);
                float p1 = __builtin_amdgcn_exp2f(s1[sub][e]);
                s0[sub][e] = p0; s1[sub][e] = p1;
                lrun0[e] += p0; lrun1[e] += p1;
            }

        // P -> per-wave LDS (rows 0-15 = qh0, 16-31 = qh1)
#pragma unroll
        for (int e = 0; e < 4; ++e) {
            uint2 u0, u1;
            u0.x = pk2bf(s0[0][e], s0[1][e]);
            u0.y = pk2bf(s0[2][e], s0[3][e]);
            u1.x = pk2bf(s1[0][e], s1[1][e]);
            u1.y = pk2bf(s1[2][e], s1[3][e]);
            *(uint2*)(Pw + (quad * 4 + e) * PP + mrow * 4) = u0;
            *(uint2*)(Pw + (16 + quad * 4 + e) * PP + mrow * 4) = u1;
        }

        // PV: each V fragment read feeds 2 MFMAs
#pragma unroll
        for (int jc = 0; jc < 2; ++jc) {
            frag8 af0 = *(const frag8*)(Pw + mrow * PP + jc * 32 + quad * 8);
            frag8 af1 = *(const frag8*)(Pw + (16 + mrow) * PP + jc * 32 + quad * 8);
            int c = jc * 4 + quad;
#pragma unroll
            for (int t = 0; t < DHT; ++t) {
                frag8 bfr = *(const frag8*)(VsB + ((size_t)((t * 16 + mrow) * 8 + (c ^ (mrow & 7)))) * 8);
                oacc0[t] = __builtin_amdgcn_mfma_f32_16x16x32_bf16(af0, bfr, oacc0[t], 0, 0, 0);
                oacc1[t] = __builtin_amdgcn_mfma_f32_16x16x32_bf16(af1, bfr, oacc1[t], 0, 0, 0);
            }
        }
        __syncthreads();
        p ^= 1;
    }

    lrun0 = bfly_add16(lrun0);
    lrun1 = bfly_add16(lrun1);
    f32x4 linv0, linv1;
#pragma unroll
    for (int e = 0; e < 4; ++e) { linv0[e] = 1.0f / lrun0[e]; linv1[e] = 1.0f / lrun1[e]; }
#pragma unroll
    for (int t = 0; t < DHT; ++t) {
        int d = t * 16 + mrow;
        if (d >= DH) continue;
#pragma unroll
        for (int e = 0; e < 4; ++e) {
            int n0 = qb + wave * 32 + quad * 4 + e;
            int n1 = n0 + 16;
            if (n0 < N)
                O[((size_t)(b * N + n0)) * E + h * DH + d] = f2bf(oacc0[t][e] * linv0[e]);
            if (n1 < N)
                O[((size_t)(b * N + n1)) * E + h * DH + d] = f2bf(oacc1[t][e] * linv1[e]);
        }
    }
}

// s3 attention body (DH=96, N=49): single-tile padded-LDS path
__device__ __forceinline__ void attn_s3_body(bf16u* __restrict__ smem,
                                             const bf16u* __restrict__ Qg, const bf16u* __restrict__ Kg,
                                             const bf16u* __restrict__ Vtg, bf16u* __restrict__ Og,
                                             int lin) {
    constexpr int DH = 96, N = 49, DHP = 96, KC = 3, DHT = 6, NJc = 64, E = 768;
    constexpr int KP = 104, QP = 104, VP = 72, PP = 72, C8 = 12;
    bf16u* Ks = smem;
    bf16u* Vs = Ks + 64 * KP;
    bf16u* QsPw = Vs + DHT * 16 * VP;

    const bf16u* Q = Qg + xoff[3];
    const bf16u* K = Kg + xoff[3];
    const bf16u* Vt = Vtg + voff[3];
    bf16u* O = Og + xoff[3];

    int h = lin & 7, b = lin >> 3;
    int tid = threadIdx.x, wave = tid >> 6, lane = tid & 63;
    int mrow = lane & 15, quad = lane >> 4;

    for (int idx = tid; idx < 64 * C8; idx += 256) {
        int row = idx / C8, col = (idx % C8) * 8;
        int n = row; if (n >= N) n = N - 1;
        frag8 v = {};
        if (col < DH) v = *(const frag8*)(Q + ((size_t)(b * N + n)) * E + h * DH + col);
        *(frag8*)(QsPw + row * QP + col) = v;
    }
    for (int idx = tid; idx < 64 * C8; idx += 256) {
        int row = idx / C8, col = (idx % C8) * 8;
        int n = row; if (n >= N) n = N - 1;
        frag8 v = {};
        if (col < DH) v = *(const frag8*)(K + (size_t)(b * N + n) * E + h * DH + col);
        *(frag8*)(Ks + row * KP + col) = v;
    }
    const bf16u* Vb2 = Vt + (size_t)(b * 8 + h) * DHP * NJc;
    for (int idx = tid; idx < DHT * 16 * 8; idx += 256) {
        int d = idx / 8, j = (idx % 8) * 8;
        frag8 v = {};
        if (d < DH) v = *(const frag8*)(Vb2 + (size_t)d * NJc + j);
        *(frag8*)(Vs + d * VP + j) = v;
    }
    __syncthreads();
    frag8 qf[KC];
#pragma unroll
    for (int kc = 0; kc < KC; ++kc)
        qf[kc] = *(const frag8*)(QsPw + (wave * 16 + mrow) * QP + kc * 32 + quad * 8);
    __syncthreads();
    bf16u* Pw = QsPw + wave * 16 * PP;

    f32x4 lrun = {0.f, 0.f, 0.f, 0.f};
    f32x4 oacc[DHT];
#pragma unroll
    for (int t = 0; t < DHT; ++t) oacc[t] = f32x4{0.f, 0.f, 0.f, 0.f};

    f32x4 s[4];
#pragma unroll
    for (int sub = 0; sub < 4; ++sub) {
        f32x4 acc = {};
#pragma unroll
        for (int kc = 0; kc < KC; ++kc) {
            frag8 bfr = *(const frag8*)(Ks + (sub * 16 + mrow) * KP + kc * 32 + quad * 8);
            acc = __builtin_amdgcn_mfma_f32_16x16x32_bf16(qf[kc], bfr, acc, 0, 0, 0);
        }
        int col = sub * 16 + mrow;
        if (col >= N) { acc[0] = acc[1] = acc[2] = acc[3] = -30000.f; }
        s[sub] = acc;
    }
#pragma unroll
    for (int sub = 0; sub < 4; ++sub)
#pragma unroll
        for (int e = 0; e < 4; ++e) {
            float px = __builtin_amdgcn_exp2f(s[sub][e]);
            s[sub][e] = px;
            lrun[e] += px;
        }
#pragma unroll
    for (int e = 0; e < 4; ++e) {
        uint2 u;
        u.x = pk2bf(s[0][e], s[1][e]);
        u.y = pk2bf(s[2][e], s[3][e]);
        *(uint2*)(Pw + (quad * 4 + e) * PP + mrow * 4) = u;
    }
#pragma unroll
    for (int jc = 0; jc < 2; ++jc) {
        frag8 af = *(const frag8*)(Pw + mrow * PP + jc * 32 + quad * 8);
#pragma unroll
        for (int t = 0; t < DHT; ++t) {
            frag8 bfr = *(const frag8*)(Vs + (t * 16 + mrow) * VP + jc * 32 + quad * 8);
            oacc[t] = __builtin_amdgcn_mfma_f32_16x16x32_bf16(af, bfr, oacc[t], 0, 0, 0);
        }
    }

    lrun = bfly_add16(lrun);
    f32x4 linv;
#pragma unroll
    for (int e = 0; e < 4; ++e) linv[e] = 1.0f / lrun[e];
#pragma unroll
    for (int t = 0; t < DHT; ++t) {
        int d = t * 16 + mrow;
#pragma unroll
        for (int e = 0; e < 4; ++e) {
            int n = wave * 16 + quad * 4 + e;
            if (n < N)
                O[((size_t)(b * N + n)) * E + h * DH + d] = f2bf(oacc[t][e] * linv[e]);
        }
    }
}

// Merged attention: 0..2047 = fat (per-segment balanced XCD swizzle),
// 2048..2175 = s3 (absorbed; hides under fat tail).
__global__ __launch_bounds__(256, 3) void attn_all(const bf16u* __restrict__ Qb, const bf16u* __restrict__ Kb,
                                                   const bf16u* __restrict__ Vt, bf16u* __restrict__ Ob) {
    __shared__ __align__(16) bf16u smem[23552];   // fat: 2*896*8 + 4*32*72; s3 uses 20224
    int g = blockIdx.x;
    if (g < 896) {
        int l = (g & 7) * 112 + (g >> 3);
        attn_body3<48, 784>(smem, Qb + xoff[0], Kb + xoff[0], Vt + voff[0], Ob + xoff[0], l);
    } else if (g < 1792) {
        int gg = g - 896;
        int l = (gg & 7) * 112 + (gg >> 3);
        attn_body3<24, 784>(smem, Qb + xoff[1], Kb + xoff[1], Vt + voff[1], Ob + xoff[1], l);
    } else if (g < 2048) {
        int gg = g - 1792;
        int l = (gg & 7) * 32 + (gg >> 3);
        attn_body3<48, 196>(smem, Qb + xoff[2], Kb + xoff[2], Vt + voff[2], Ob + xoff[2], l);
    } else {
        attn_s3_body(smem, Qb, Kb, Vt, Ob, g - 2048);
    }
}

// ---------------------------------------------------------------------------
// Fused O-GEMM + unflatten + residual (unchanged)
// ---------------------------------------------------------------------------
template<int SC>
__device__ __forceinline__ size_t out_index(int rowg, int cg) {
    if (SC == 0) {
        int b = rowg / 784, n = rowg - b * 784;
        int slot = cg / 96, c = cg - slot * 96;
        int hh = n / 28, ww = n - hh * 28;
        return ((size_t)(b * 96 + c) * 56 + 2 * hh + (slot >> 1)) * 56 + 2 * ww + (slot & 1);
    } else if (SC == 1) {
        int b = rowg / 784, n = rowg - b * 784;
        return ((size_t)(b * 192 + cg)) * 784 + n;
    } else if (SC == 2) {
        int b = rowg / 196, n = rowg - b * 196;
        return ((size_t)(b * 384 + cg)) * 196 + n;
    } else {
        int b = rowg / 49, n = rowg - b * 49;
        return ((size_t)(b * 768 + cg)) * 49 + n;
    }
}

template<int SC>
__device__ __forceinline__ void o_tile128(const bf16u* __restrict__ A, const bf16u* __restrict__ W,
                                          const float* __restrict__ bias,
                                          const float* __restrict__ xd, float* __restrict__ out,
                                          int M, int E, int mTile, int eTile, bf16u* sm) {
    bf16u* A0 = sm;
    bf16u* B0 = sm + 4096;
    bf16u* A1 = sm + 8192;
    bf16u* B1 = sm + 12288;
    int tid = threadIdx.x, wave = tid >> 6, lane = tid & 63;
    int mbase = mTile * 128, ebase = eTile * 128;
    int wm = (wave & 1) * 64, wn = (wave >> 1) * 64;
    int mrow = lane & 15, quad = lane >> 4;
    f32x4 acc[4][4] = {};
    int srow = tid >> 2, sch = (tid & 3) * 8;
    int K = E;
    int m0 = mbase + srow;      if (m0 >= M) m0 = M - 1;
    int m1 = mbase + srow + 64; if (m1 >= M) m1 = M - 1;
    const bf16u* Ag0 = A + (size_t)m0 * K + sch;
    const bf16u* Ag1 = A + (size_t)m1 * K + sch;
    const bf16u* Wg0 = W + (size_t)(ebase + srow) * K + sch;
    const bf16u* Wg1 = W + (size_t)(ebase + srow + 64) * K + sch;
    int la = mrow * 32 + quad * 8;

    auto stage = [&](int k0, bf16u* As, bf16u* Bs) {
        async_cp16(Ag0 + k0, As + tid * 8);
        async_cp16(Ag1 + k0, As + 2048 + tid * 8);
        async_cp16(Wg0 + k0, Bs + tid * 8);
        async_cp16(Wg1 + k0, Bs + 2048 + tid * 8);
    };
    auto compute = [&](const bf16u* As, const bf16u* Bs) {
        frag8 af[4], bfr[4];
#pragma unroll
        for (int i = 0; i < 4; ++i) {
            af[i]  = *(const frag8*)(As + (wm + i * 16) * 32 + la);
            bfr[i] = *(const frag8*)(Bs + (wn + i * 16) * 32 + la);
        }
#pragma unroll
        for (int i = 0; i < 4; ++i)
#pragma unroll
            for (int j = 0; j < 4; ++j)
                acc[i][j] = __builtin_amdgcn_mfma_f32_16x16x32_bf16(af[i], bfr[j], acc[i][j], 0, 0, 0);
    };

    stage(0, A0, B0);
    __syncthreads();
    for (int k0 = 0; k0 < K; k0 += 64) {
        stage(k0 + 32, A1, B1);
        compute(A0, B0);
        __syncthreads();
        if (k0 + 64 < K) stage(k0 + 64, A0, B0);
        compute(A1, B1);
        if (k0 + 64 < K) __syncthreads();
    }

    float* Ls = (float*)sm;   // 32 x 133
#pragma unroll
    for (int ph = 0; ph < 4; ++ph) {
        __syncthreads();
        if ((wave & 1) == (ph >> 1)) {
            int mt0 = (ph & 1) * 2;
#pragma unroll
            for (int mi = 0; mi < 2; ++mi) {
                int mt = mt0 + mi;
#pragma unroll
                for (int nt = 0; nt < 4; ++nt)
#pragma unroll
                    for (int r = 0; r < 4; ++r)
                        Ls[(mi * 16 + quad * 4 + r) * 133 + wn + nt * 16 + mrow] = acc[mt][nt][r];
            }
        }
        __syncthreads();
        int rb = mbase + ph * 32;
#pragma unroll
        for (int i = 0; i < 16; ++i) {
            int coll = (tid >> 5) + i * 8;
            int l = tid & 31;
            int rg = rb + l;
            if (rg < M) {
                int cg = ebase + coll;
                size_t oi = out_index<SC>(rg, cg);
                out[oi] = xd[oi] + Ls[l * 133 + coll] + bias[cg];
            }
        }
    }
}

__device__ __forceinline__ void o_tile64_s1(const bf16u* __restrict__ A, const bf16u* __restrict__ W,
                                            const float* __restrict__ bias,
                                            const float* __restrict__ xd, float* __restrict__ out,
                                            int M, int E, int mTile, int eTile, bf16u* sm) {
    bf16u* A0 = sm;
    bf16u* B0 = sm + 2048;
    bf16u* A1 = sm + 4096;
    bf16u* B1 = sm + 6144;
    int tid = threadIdx.x, wave = tid >> 6, lane = tid & 63;
    int mbase = mTile * 64, ebase = eTile * 64;
    int wm = (wave & 1) * 32, wn = (wave >> 1) * 32;
    int mrow = lane & 15, quad = lane >> 4;
    f32x4 acc[2][2] = {};
    int srow = tid >> 2, sch = (tid & 3) * 8;
    int K = E;
    int m = mbase + srow; if (m >= M) m = M - 1;
    const bf16u* Ag = A + (size_t)m * K + sch;
    const bf16u* Wg = W + (size_t)(ebase + srow) * K + sch;
    int la = mrow * 32 + quad * 8;

    auto stage = [&](int k0, bf16u* As, bf16u* Bs) {
        async_cp16(Ag + k0, As + tid * 8);
        async_cp16(Wg + k0, Bs + tid * 8);
    };
    auto compute = [&](const bf16u* As, const bf16u* Bs) {
        frag8 af0 = *(const frag8*)(As + wm * 32 + la);
        frag8 af1 = *(const frag8*)(As + (wm + 16) * 32 + la);
        frag8 bf0 = *(const frag8*)(Bs + wn * 32 + la);
        frag8 bf1 = *(const frag8*)(Bs + (wn + 16) * 32 + la);
        acc[0][0] = __builtin_amdgcn_mfma_f32_16x16x32_bf16(af0, bf0, acc[0][0], 0, 0, 0);
        acc[0][1] = __builtin_amdgcn_mfma_f32_16x16x32_bf16(af0, bf1, acc[0][1], 0, 0, 0);
        acc[1][0] = __builtin_amdgcn_mfma_f32_16x16x32_bf16(af1, bf0, acc[1][0], 0, 0, 0);
        acc[1][1] = __builtin_amdgcn_mfma_f32_16x16x32_bf16(af1, bf1, acc[1][1], 0, 0, 0);
    };

    stage(0, A0, B0);
    __syncthreads();
    for (int k0 = 0; k0 < K; k0 += 64) {
        stage(k0 + 32, A1, B1);
        compute(A0, B0);
        __syncthreads();
        if (k0 + 64 < K) stage(k0 + 64, A0, B0);
        compute(A1, B1);
        if (k0 + 64 < K) __syncthreads();
    }

    float* Ls = (float*)sm;   // 32 x 69
#pragma unroll
    for (int ph = 0; ph < 2; ++ph) {
        __syncthreads();
        if ((wave & 1) == ph) {
#pragma unroll
            for (int mt = 0; mt < 2; ++mt)
#pragma unroll
                for (int nt = 0; nt < 2; ++nt)
#pragma unroll
                    for (int r = 0; r < 4; ++r)
                        Ls[(mt * 16 + quad * 4 + r) * 69 + wn + nt * 16 + mrow] = acc[mt][nt][r];
        }
        __syncthreads();
        int rb = mbase + ph * 32;
#pragma unroll
        for (int i = 0; i < 8; ++i) {
            int coll = (tid >> 5) + i * 8;
            int l = tid & 31;
            int rg = rb + l;
            if (rg < M) {
                int cg = ebase + coll;
                size_t oi = out_index<1>(rg, cg);
                out[oi] = xd[oi] + Ls[l * 69 + coll] + bias[cg];
            }
        }
    }
}

__global__ __launch_bounds__(256) void ounf_fat(const bf16u* __restrict__ Ob, const bf16u* __restrict__ Wb,
                                                float* __restrict__ out, BiasP bp, OunfP up) {
    __shared__ __align__(16) bf16u sm[16384];   // 2 x (As+Bs); epilogue reuses as fp32 Ls
    int blk = blockIdx.x;
    int seg = 0;
    while (seg < 3 && blk >= oStart[seg + 1]) seg++;
    int t = blk - oStart[seg];
    if (seg < 3) {
        int s = (seg == 0) ? 0 : (seg == 1 ? 2 : 3);
        int E = cE[s], M = cM[s];
        int ct = E >> 7;
        int mTile = t / ct, eTile = t - mTile * ct;
        const bf16u* A = Ob + xoff[s];
        const bf16u* W = Wb + woff[s] + (size_t)3 * E * E;
        if (s == 0)
            o_tile128<0>(A, W, bp.p[3], up.xd[0], out + xoff[0], M, E, mTile, eTile, sm);
        else if (s == 2)
            o_tile128<2>(A, W, bp.p[11], up.xd[2], out + xoff[2], M, E, mTile, eTile, sm);
        else
            o_tile128<3>(A, W, bp.p[15], up.xd[3], out + xoff[3], M, E, mTile, eTile, sm);
    } else {
        int E = 192, M = 12544;
        int mTile = t / 3, eTile = t - mTile * 3;
        o_tile64_s1(Ob + xoff[1], Wb + woff[1] + (size_t)3 * E * E, bp.p[7],
                    up.xd[1], out + xoff[1], M, E, mTile, eTile, sm);
    }
}

// ---------------------------------------------------------------------------
// Host launch — 4 dispatches
// ---------------------------------------------------------------------------
extern "C" void kernel_launch(void* const* d_in, const int* in_sizes, int n_in,
                              void* d_out, int out_size, void* d_ws, size_t ws_size,
                              hipStream_t stream) {
    bf16u* ws = (bf16u*)d_ws;
    bf16u* Qb = ws;
    bf16u* Kb = ws + 9031680;
    bf16u* Vt = ws + 18063360;
    bf16u* Ob = ws + 31170560;
    bf16u* Wb = ws + 40202240;
    bf16u* Xd = ws + 43888640;
    bf16u* Xc = ws + 52920320;
    float* out = (float*)d_out;

    PrepP pp; BiasP bb; OunfP ux;
    for (int s = 0; s < 4; ++s) {
        pp.x[s * 2]     = (const float*)d_in[s * 2];
        pp.x[s * 2 + 1] = (const float*)d_in[s * 2 + 1];
        ux.xd[s]        = (const float*)d_in[s * 2];
        int w0 = 8 + s * 8;
        pp.w[s * 4 + 0] = (const float*)d_in[w0 + 0];
        pp.w[s * 4 + 1] = (const float*)d_in[w0 + 2];
        pp.w[s * 4 + 2] = (const float*)d_in[w0 + 4];
        pp.w[s * 4 + 3] = (const float*)d_in[w0 + 6];
        bb.p[s * 4 + 0] = (const float*)d_in[w0 + 1];
        bb.p[s * 4 + 1] = (const float*)d_in[w0 + 3];
        bb.p[s * 4 + 2] = (const float*)d_in[w0 + 5];
        bb.p[s * 4 + 3] = (const float*)d_in[w0 + 7];
    }

    prep<<<20424, 256, 0, stream>>>(pp, Xd, Xc, Wb);
    qkv_all<<<2802, 256, 0, stream>>>(Xd, Xc, Wb, Qb, Kb, Vt, bb);
    attn_all<<<2176, 256, 0, stream>>>(Qb, Kb, Vt, Ob);
    ounf_fat<<<999, 256, 0, stream>>>(Ob, Wb, out, bb, ux);
}